// Round 22
// baseline (444.178 us; speedup 1.0000x reference)
//
#include <hip/hip_runtime.h>
#include <math.h>

#define N_NODES 100000
#define N_EDGES 3200000
#define D_FEAT 256
#define GC_HID 20
#define DEC_HID 40
#define Z_DIM 32

#define EPB 2048          // edges per sort block
#define NBLK 1563         // ceil(3.2M / 2048)
#define SB 392            // node buckets of 256 (392*256 = 100352)
#define SBSH 8
#define S2CAP 12288       // per-bucket record cap
#define GF_THREADS 192

// ---------------- ws layout (bytes) ----------------
// h_pre  @ 0           8,000,000
// agg    @ 8,000,000   8,000,000
// dbuf   @ 0          16,000,000   (overlays h_pre+agg when dead)
// grec   @16,000,000  12,804,096
// rec_r  @28,804,096  12,804,096   (pml bf16 [N][64]=12.8MB overlays post-gscat)
// srow_r @41,608,192   1,228,518   (zbuf overlays post-gather)
// pref_t @42,836,720   2,450,784
// row_ptr@45,287,504     400,004
// gtot   @45,687,508       1,568
// gbase  @45,689,076       1,572
// rs_s   @45,690,648     400,000
// rec_s  @46,090,648   3,201,024
// srow_s @49,291,672   1,228,518
// Wpack  @50,520,192      98,304   end = 50,618,496

__device__ inline unsigned short f2bf(float f) {
    unsigned u = __float_as_uint(f);
    return (unsigned short)((u + 0x7FFFu + ((u >> 16) & 1u)) >> 16);
}
__device__ inline float bf2f(unsigned short h) {
    return __uint_as_float((unsigned)h << 16);
}

// pack node-row weights: Wpack[k][0:20]=W1[k], [24:56]=Wmu[20+k], [56:88]=Wls[20+k]
__global__ __launch_bounds__(96) void k_wpack(const float* __restrict__ W1,
                                              const float* __restrict__ Wmu,
                                              const float* __restrict__ Wls,
                                              float* __restrict__ Wp) {
    int k = blockIdx.x, j = threadIdx.x;
    float v = 0.0f;
    if (j < 20) v = W1[k * GC_HID + j];
    else if (j >= 24 && j < 56) v = Wmu[(GC_HID + k) * Z_DIM + (j - 24)];
    else if (j >= 56 && j < 88) v = Wls[(GC_HID + k) * Z_DIM + (j - 56)];
    Wp[k * 96 + j] = v;
}

// dual block-local counting sort (receiver u32 + sender u8 streams).
// ZERO global atomics (R13: each device-scope atomic = memory-side write).
__global__ __launch_bounds__(512) void k_sort(const int* __restrict__ snd,
                                              const int* __restrict__ rcv,
                                              unsigned* __restrict__ rec_r,
                                              unsigned char* __restrict__ rec_s,
                                              unsigned short* __restrict__ srow_r,
                                              unsigned short* __restrict__ srow_s) {
    __shared__ int es[EPB], er[EPB];
    __shared__ unsigned scan[SB + 1];
    __shared__ unsigned cur[SB];
    __shared__ unsigned sorted[EPB];
    __shared__ unsigned char sorteds[EPB];
    int b = blockIdx.x, t = threadIdx.x;
    int base = b * EPB;
    int cnt = min(EPB, N_EDGES - base);
    for (int i = t; i < cnt; i += 512) { es[i] = snd[base + i]; er[i] = rcv[base + i]; }

    for (int i = t; i < SB + 1; i += 512) scan[i] = 0u;
    __syncthreads();
    for (int i = t; i < cnt; i += 512) atomicAdd(&scan[(er[i] >> SBSH) + 1], 1u);
    __syncthreads();
    for (int off = 1; off < SB + 1; off <<= 1) {
        unsigned v = (t >= off && t < SB + 1) ? scan[t - off] : 0u;
        __syncthreads();
        if (t < SB + 1) scan[t] += v;
        __syncthreads();
    }
    for (int i = t; i < SB + 1; i += 512) srow_r[(size_t)b * (SB + 1) + i] = (unsigned short)scan[i];
    if (t < SB) cur[t] = scan[t];
    __syncthreads();
    for (int i = t; i < cnt; i += 512) {
        int r = er[i];
        unsigned pos = atomicAdd(&cur[r >> SBSH], 1u);
        sorted[pos] = ((unsigned)(r & 255) << 17) | (unsigned)es[i];
    }
    __syncthreads();
    for (int i = t; i < cnt; i += 512) rec_r[(size_t)base + i] = sorted[i];
    __syncthreads();

    for (int i = t; i < SB + 1; i += 512) scan[i] = 0u;
    __syncthreads();
    for (int i = t; i < cnt; i += 512) atomicAdd(&scan[(es[i] >> SBSH) + 1], 1u);
    __syncthreads();
    for (int off = 1; off < SB + 1; off <<= 1) {
        unsigned v = (t >= off && t < SB + 1) ? scan[t - off] : 0u;
        __syncthreads();
        if (t < SB + 1) scan[t] += v;
        __syncthreads();
    }
    for (int i = t; i < SB + 1; i += 512) srow_s[(size_t)b * (SB + 1) + i] = (unsigned short)scan[i];
    if (t < SB) cur[t] = scan[t];
    __syncthreads();
    for (int i = t; i < cnt; i += 512) {
        int s = es[i];
        unsigned pos = atomicAdd(&cur[s >> SBSH], 1u);
        sorteds[pos] = (unsigned char)(s & 255);
    }
    __syncthreads();
    for (int i = t; i < cnt; i += 512) rec_s[(size_t)base + i] = sorteds[i];
}

// sender-degree via per-bucket LDS histogram over sender-sorted runs
__global__ __launch_bounds__(512) void k_degs(const unsigned char* __restrict__ rec_s,
                                              const unsigned short* __restrict__ srow_s,
                                              float* __restrict__ rs_s) {
    __shared__ unsigned h[256];
    int s = blockIdx.x, t = threadIdx.x;
    if (t < 256) h[t] = 0u;
    __syncthreads();
    for (int k = t; k < NBLK; k += 512) {
        const unsigned short* row = srow_s + (size_t)k * (SB + 1);
        unsigned st = row[s], en = row[s + 1];
        const unsigned char* rp = rec_s + (size_t)k * EPB;
        for (unsigned i = st; i < en; ++i) atomicAdd(&h[rp[i]], 1u);
    }
    __syncthreads();
    if (t < 256) {
        int n = (s << SBSH) + t;
        if (n < N_NODES) rs_s[n] = rsqrtf(fmaxf((float)h[t], 1.0f));
    }
}

// per-bucket prefix over block segments: pref_t[s][k], totals gtot[s]
__global__ __launch_bounds__(256) void k_scanB(const unsigned short* __restrict__ srow_r,
                                               unsigned* __restrict__ pref_t,
                                               unsigned* __restrict__ gtot) {
    __shared__ unsigned buf[256];
    int s = blockIdx.x, t = threadIdx.x;
    unsigned run = 0;
    for (int k0 = 0; k0 < NBLK; k0 += 256) {
        int k = k0 + t;
        unsigned v = 0;
        if (k < NBLK) {
            const unsigned short* row = srow_r + (size_t)k * (SB + 1);
            v = (unsigned)row[s + 1] - (unsigned)row[s];
        }
        buf[t] = v;
        __syncthreads();
        for (int off = 1; off < 256; off <<= 1) {
            unsigned x = (t >= off) ? buf[t - off] : 0u;
            __syncthreads();
            buf[t] += x;
            __syncthreads();
        }
        if (k < NBLK) pref_t[(size_t)s * NBLK + k] = run + (buf[t] - v);
        unsigned tot = buf[255];
        __syncthreads();
        run += tot;
    }
    if (t == 0) gtot[s] = run;
}

// exclusive scan of bucket totals -> gbase[SB+1]
__global__ __launch_bounds__(512) void k_scanG(const unsigned* __restrict__ gtot,
                                               unsigned* __restrict__ gbase) {
    __shared__ unsigned buf[SB];
    int t = threadIdx.x;
    if (t < SB) buf[t] = gtot[t];
    __syncthreads();
    for (int off = 1; off < SB; off <<= 1) {
        unsigned x = (t >= off && t < SB) ? buf[t - off] : 0u;
        __syncthreads();
        if (t < SB) buf[t] += x;
        __syncthreads();
    }
    if (t < SB) gbase[t + 1] = buf[t];
    if (t == 0) gbase[0] = 0u;
}

// scatter block-sorted records to global bucket-sorted order
__global__ __launch_bounds__(256) void k_gscat(const unsigned* __restrict__ rec_r,
                                               const unsigned short* __restrict__ srow_r,
                                               const unsigned* __restrict__ pref_t,
                                               const unsigned* __restrict__ gbase,
                                               unsigned* __restrict__ grec) {
    __shared__ unsigned recs[EPB];
    __shared__ unsigned short srow[SB + 1];
    int b = blockIdx.x, t = threadIdx.x;
    int base = b * EPB;
    int cnt = min(EPB, N_EDGES - base);
    for (int i = t; i < cnt; i += 256) recs[i] = rec_r[(size_t)base + i];
    for (int i = t; i < SB + 1; i += 256) srow[i] = srow_r[(size_t)b * (SB + 1) + i];
    __syncthreads();
    for (int s = t; s < SB; s += 256) {
        unsigned lo = srow[s], hi = srow[s + 1];
        if (lo == hi) continue;
        unsigned dst = gbase[s] + pref_t[(size_t)s * NBLK + b];
        for (unsigned i = lo; i < hi; ++i) grec[dst + (i - lo)] = recs[i];
    }
}

// within-bucket counting sort by local receiver (in-place) + CSR row_ptr
__global__ __launch_bounds__(256) void k_sort2(unsigned* __restrict__ grec,
                                               const unsigned* __restrict__ gbase,
                                               unsigned* __restrict__ row_ptr) {
    __shared__ unsigned recs[S2CAP];     // 48 KB
    __shared__ unsigned hist[256];
    __shared__ unsigned scan[256];
    __shared__ unsigned cur[256];
    int s = blockIdx.x, t = threadIdx.x;
    unsigned lo = gbase[s], hi = gbase[s + 1];
    unsigned cnt = min(hi - lo, (unsigned)S2CAP);
    for (unsigned i = t; i < cnt; i += 256) recs[i] = grec[lo + i];
    hist[t] = 0u;
    __syncthreads();
    for (unsigned i = t; i < cnt; i += 256) atomicAdd(&hist[recs[i] >> 17], 1u);
    __syncthreads();
    unsigned v = hist[t];
    scan[t] = v;
    __syncthreads();
    for (int off = 1; off < 256; off <<= 1) {
        unsigned x = (t >= off) ? scan[t - off] : 0u;
        __syncthreads();
        scan[t] += x;
        __syncthreads();
    }
    unsigned excl = scan[t] - v;
    {
        int n = (s << SBSH) + t;
        if (n <= N_NODES) row_ptr[n] = lo + excl;
    }
    cur[t] = excl;
    __syncthreads();
    for (unsigned i = t; i < cnt; i += 256) {
        unsigned rec = recs[i];
        unsigned pos = atomicAdd(&cur[rec >> 17], 1u);
        grec[lo + pos] = rec & 0x1FFFFu;
    }
}

// pure CSR gather: 5 lanes per node, one float4 each; zero atomics.
__global__ __launch_bounds__(320) void k_gather(const unsigned* __restrict__ row_ptr,
                                                const unsigned* __restrict__ grec,
                                                const float* __restrict__ src,
                                                float* __restrict__ dst) {
    int gid = blockIdx.x * 320 + threadIdx.x;
    int node = gid / 5, q = gid % 5;
    if (node >= N_NODES) return;
    unsigned lo = row_ptr[node], hi = row_ptr[node + 1];
    float4 a0 = make_float4(0.f, 0.f, 0.f, 0.f);
    float4 a1 = make_float4(0.f, 0.f, 0.f, 0.f);
    float4 a2 = make_float4(0.f, 0.f, 0.f, 0.f);
    float4 a3 = make_float4(0.f, 0.f, 0.f, 0.f);
    unsigned e = lo;
    for (; e + 4 <= hi; e += 4) {
        unsigned s0 = grec[e], s1 = grec[e + 1], s2 = grec[e + 2], s3 = grec[e + 3];
        float4 v0 = ((const float4*)src)[s0 * 5 + q];
        float4 v1 = ((const float4*)src)[s1 * 5 + q];
        float4 v2 = ((const float4*)src)[s2 * 5 + q];
        float4 v3 = ((const float4*)src)[s3 * 5 + q];
        a0.x += v0.x; a0.y += v0.y; a0.z += v0.z; a0.w += v0.w;
        a1.x += v1.x; a1.y += v1.y; a1.z += v1.z; a1.w += v1.w;
        a2.x += v2.x; a2.y += v2.y; a2.z += v2.z; a2.w += v2.w;
        a3.x += v3.x; a3.y += v3.y; a3.z += v3.z; a3.w += v3.w;
    }
    for (; e < hi; ++e) {
        unsigned s0 = grec[e];
        float4 v0 = ((const float4*)src)[s0 * 5 + q];
        a0.x += v0.x; a0.y += v0.y; a0.z += v0.z; a0.w += v0.w;
    }
    a0.x += a1.x + a2.x + a3.x;
    a0.y += a1.y + a2.y + a3.y;
    a0.z += a1.z + a2.z + a3.z;
    a0.w += a1.w + a2.w + a3.w;
    float sc = rsqrtf(fmaxf((float)(hi - lo), 1.0f));
    a0.x *= sc; a0.y *= sc; a0.z *= sc; a0.w *= sc;
    ((float4*)dst)[node * 5 + q] = a0;
}

// FUSED gc1 + encoder-partials, v6: register-blocked GEMM, both operands
// in LDS (R21 lesson: weight s_load stream was the stall -- K$ misses
// expose ~200cy per 48cy of FMA). Thread = 4 nodes x 8 outs (acc[4][8]);
// per k: 1 b128 x-read (transposed xT[k][node]) + 2 b128 w-reads
// (wT[k][col], wave-broadcast) + 32 FMA. 192 thr = 16 ng x 12 og.
// 43 KB LDS -> 3 blocks/CU; double-buffered with register prefetch.
__global__ __launch_bounds__(192) void k_gc1f(const float* __restrict__ nodes,
                                              const float* __restrict__ Wp,
                                              const float* __restrict__ b1,
                                              const float* __restrict__ rs_s,
                                              float* __restrict__ h_pre,
                                              unsigned short* __restrict__ pml) {
    __shared__ float xT[2][32 * 68];    // [k][node] transposed; 8,704 B each
    __shared__ float wT[2][32 * 100];   // [k][col] padded;     12,800 B each
    int t = threadIdx.x;
    int ng = t & 15;            // node group: nodes ng*4 .. +3
    int og = t >> 4;            // out group: cols og*8 .. +7  (0..11)
    int n0 = blockIdx.x * 64;

    float acc[4][8];
#pragma unroll
    for (int i = 0; i < 4; ++i)
#pragma unroll
        for (int j = 0; j < 8; ++j) acc[i][j] = 0.0f;

    // ---- stage chunk 0 ----
    for (int idx = t; idx < 512; idx += GF_THREADS) {
        int rr = idx >> 3, c4 = idx & 7;
        int gn = n0 + rr;
        float4 v = (gn < N_NODES)
            ? ((const float4*)nodes)[(size_t)gn * 64 + c4]
            : make_float4(0.f, 0.f, 0.f, 0.f);
        xT[0][(c4 * 4 + 0) * 68 + rr] = v.x;
        xT[0][(c4 * 4 + 1) * 68 + rr] = v.y;
        xT[0][(c4 * 4 + 2) * 68 + rr] = v.z;
        xT[0][(c4 * 4 + 3) * 68 + rr] = v.w;
    }
    for (int idx = t; idx < 768; idx += GF_THREADS) {
        int kk = idx / 24, q = idx - kk * 24;
        float4 v = ((const float4*)Wp)[(size_t)kk * 24 + q];
        *(float4*)&wT[0][kk * 100 + q * 4] = v;
    }
    __syncthreads();

    for (int c = 0; c < 8; ++c) {
        float4 px[3], pw[4];
        if (c < 7) {
            int idx = t;
#pragma unroll
            for (int r = 0; r < 3; ++r, idx += GF_THREADS) {
                if (idx < 512) {
                    int rr = idx >> 3, c4 = idx & 7;
                    int gn = n0 + rr;
                    px[r] = (gn < N_NODES)
                        ? ((const float4*)nodes)[(size_t)gn * 64 + (c + 1) * 8 + c4]
                        : make_float4(0.f, 0.f, 0.f, 0.f);
                }
            }
            idx = t;
#pragma unroll
            for (int r = 0; r < 4; ++r, idx += GF_THREADS) {
                int kk = idx / 24, q = idx - kk * 24;
                pw[r] = ((const float4*)Wp)[((size_t)(c + 1) * 32 + kk) * 24 + q];
            }
        }
        const float* xb = &xT[c & 1][ng * 4];
        const float* wb = &wT[c & 1][og * 8];
#pragma unroll 4
        for (int kk = 0; kk < 32; ++kk) {
            float4 xv = *(const float4*)&xb[kk * 68];
            float4 w0 = *(const float4*)&wb[kk * 100];
            float4 w1 = *(const float4*)&wb[kk * 100 + 4];
            float xs0 = xv.x, xs1 = xv.y, xs2 = xv.z, xs3 = xv.w;
            acc[0][0] = fmaf(xs0, w0.x, acc[0][0]); acc[0][1] = fmaf(xs0, w0.y, acc[0][1]);
            acc[0][2] = fmaf(xs0, w0.z, acc[0][2]); acc[0][3] = fmaf(xs0, w0.w, acc[0][3]);
            acc[0][4] = fmaf(xs0, w1.x, acc[0][4]); acc[0][5] = fmaf(xs0, w1.y, acc[0][5]);
            acc[0][6] = fmaf(xs0, w1.z, acc[0][6]); acc[0][7] = fmaf(xs0, w1.w, acc[0][7]);
            acc[1][0] = fmaf(xs1, w0.x, acc[1][0]); acc[1][1] = fmaf(xs1, w0.y, acc[1][1]);
            acc[1][2] = fmaf(xs1, w0.z, acc[1][2]); acc[1][3] = fmaf(xs1, w0.w, acc[1][3]);
            acc[1][4] = fmaf(xs1, w1.x, acc[1][4]); acc[1][5] = fmaf(xs1, w1.y, acc[1][5]);
            acc[1][6] = fmaf(xs1, w1.z, acc[1][6]); acc[1][7] = fmaf(xs1, w1.w, acc[1][7]);
            acc[2][0] = fmaf(xs2, w0.x, acc[2][0]); acc[2][1] = fmaf(xs2, w0.y, acc[2][1]);
            acc[2][2] = fmaf(xs2, w0.z, acc[2][2]); acc[2][3] = fmaf(xs2, w0.w, acc[2][3]);
            acc[2][4] = fmaf(xs2, w1.x, acc[2][4]); acc[2][5] = fmaf(xs2, w1.y, acc[2][5]);
            acc[2][6] = fmaf(xs2, w1.z, acc[2][6]); acc[2][7] = fmaf(xs2, w1.w, acc[2][7]);
            acc[3][0] = fmaf(xs3, w0.x, acc[3][0]); acc[3][1] = fmaf(xs3, w0.y, acc[3][1]);
            acc[3][2] = fmaf(xs3, w0.z, acc[3][2]); acc[3][3] = fmaf(xs3, w0.w, acc[3][3]);
            acc[3][4] = fmaf(xs3, w1.x, acc[3][4]); acc[3][5] = fmaf(xs3, w1.y, acc[3][5]);
            acc[3][6] = fmaf(xs3, w1.z, acc[3][6]); acc[3][7] = fmaf(xs3, w1.w, acc[3][7]);
        }
        if (c < 7) {
            int idx = t;
#pragma unroll
            for (int r = 0; r < 3; ++r, idx += GF_THREADS) {
                if (idx < 512) {
                    int rr = idx >> 3, c4 = idx & 7;
                    float* dst = &xT[(c + 1) & 1][0];
                    dst[(c4 * 4 + 0) * 68 + rr] = px[r].x;
                    dst[(c4 * 4 + 1) * 68 + rr] = px[r].y;
                    dst[(c4 * 4 + 2) * 68 + rr] = px[r].z;
                    dst[(c4 * 4 + 3) * 68 + rr] = px[r].w;
                }
            }
            idx = t;
#pragma unroll
            for (int r = 0; r < 4; ++r, idx += GF_THREADS) {
                int kk = idx / 24, q = idx - kk * 24;
                *(float4*)&wT[(c + 1) & 1][kk * 100 + q * 4] = pw[r];
            }
            __syncthreads();
        }
    }

    // epilogue: og 0-2 park gc1 pre-acts in LDS (aliases dead xT[0]);
    // og 3-10 emit enc bf16 partials; og 11 is pad (discard).
    float* gb = &xT[0][0];     // 64 x 25
    if (og < 3) {
#pragma unroll
        for (int i = 0; i < 4; ++i)
#pragma unroll
            for (int j = 0; j < 8; ++j)
                gb[(ng * 4 + i) * 25 + og * 8 + j] = acc[i][j];
    } else if (og < 11) {
        int base = og * 8 - 24;   // 0,8,...,56
#pragma unroll
        for (int i = 0; i < 4; ++i) {
            int node = n0 + ng * 4 + i;
            if (node < N_NODES) {
                uint4 q;
                q.x = (unsigned)f2bf(acc[i][0]) | ((unsigned)f2bf(acc[i][1]) << 16);
                q.y = (unsigned)f2bf(acc[i][2]) | ((unsigned)f2bf(acc[i][3]) << 16);
                q.z = (unsigned)f2bf(acc[i][4]) | ((unsigned)f2bf(acc[i][5]) << 16);
                q.w = (unsigned)f2bf(acc[i][6]) | ((unsigned)f2bf(acc[i][7]) << 16);
                *(uint4*)(pml + (size_t)node * 64 + base) = q;
            }
        }
    }
    __syncthreads();
    if (t < 64) {
        int nn = n0 + t;
        if (nn < N_NODES) {
            float v[GC_HID];
            float mx = -1e30f;
#pragma unroll
            for (int j = 0; j < GC_HID; ++j) {
                v[j] = fmaxf(gb[t * 25 + j] + b1[j], 0.0f);
                mx = fmaxf(mx, v[j]);
            }
            float s = 0.0f;
#pragma unroll
            for (int j = 0; j < GC_HID; ++j) {
                v[j] = __expf(v[j] - mx);
                s += v[j];
            }
            float inv = rs_s[nn] / s;
#pragma unroll
            for (int j = 0; j < GC_HID; ++j) v[j] *= inv;
            float4* o = (float4*)&h_pre[(size_t)nn * GC_HID];
            o[0] = make_float4(v[0],  v[1],  v[2],  v[3]);
            o[1] = make_float4(v[4],  v[5],  v[6],  v[7]);
            o[2] = make_float4(v[8],  v[9],  v[10], v[11]);
            o[3] = make_float4(v[12], v[13], v[14], v[15]);
            o[4] = make_float4(v[16], v[17], v[18], v[19]);
        }
    }
}

// GC layer 2 transform: h2_pre = softmax(relu(h1@W2+b2)) * rs_s
__global__ __launch_bounds__(256) void k_gc2(const float* __restrict__ h1in,
                                             const float* __restrict__ W2,
                                             const float* __restrict__ b2,
                                             const float* __restrict__ rs_s,
                                             float* __restrict__ h2_pre) {
    __shared__ float Wsh[GC_HID * GC_HID];
    __shared__ float bsh[GC_HID];
    int tid = threadIdx.x;
    if (tid < GC_HID * GC_HID) Wsh[tid] = W2[tid];
    if (tid < GC_HID) bsh[tid] = b2[tid];
    __syncthreads();
    int node = blockIdx.x * 256 + tid;
    if (node >= N_NODES) return;
    const float4* ap = (const float4*)&h1in[node * GC_HID];
    float4 a0 = ap[0], a1 = ap[1], a2 = ap[2], a3 = ap[3], a4 = ap[4];
    float h1[GC_HID] = {a0.x,a0.y,a0.z,a0.w, a1.x,a1.y,a1.z,a1.w,
                        a2.x,a2.y,a2.z,a2.w, a3.x,a3.y,a3.z,a3.w,
                        a4.x,a4.y,a4.z,a4.w};
    float t[GC_HID];
#pragma unroll
    for (int j = 0; j < GC_HID; ++j) t[j] = bsh[j];
#pragma unroll
    for (int i = 0; i < GC_HID; ++i) {
        float x = h1[i];
#pragma unroll
        for (int j = 0; j < GC_HID; ++j) t[j] = fmaf(x, Wsh[i * GC_HID + j], t[j]);
    }
    float mx = -1e30f;
#pragma unroll
    for (int j = 0; j < GC_HID; ++j) { t[j] = fmaxf(t[j], 0.0f); mx = fmaxf(mx, t[j]); }
    float s = 0.0f;
#pragma unroll
    for (int j = 0; j < GC_HID; ++j) { t[j] = __expf(t[j] - mx); s += t[j]; }
    float inv = rs_s[node] / s;
#pragma unroll
    for (int j = 0; j < GC_HID; ++j) t[j] *= inv;
    float4* o = (float4*)&h2_pre[node * GC_HID];
    o[0] = make_float4(t[0],  t[1],  t[2],  t[3]);
    o[1] = make_float4(t[4],  t[5],  t[6],  t[7]);
    o[2] = make_float4(t[8],  t[9],  t[10], t[11]);
    o[3] = make_float4(t[12], t[13], t[14], t[15]);
    o[4] = make_float4(t[16], t[17], t[18], t[19]);
}

// encoder finish: mu/ls = bias + pml + h2 @ W[0:20]. Octet split,
// grid (1563, 2), block 256 = 4 waves x 64 nodes.
__global__ __launch_bounds__(256) void k_enc2(const float* __restrict__ h2in,
                                              const unsigned short* __restrict__ pml,
                                              const float* __restrict__ Wmu,
                                              const float* __restrict__ bmu,
                                              const float* __restrict__ Wls,
                                              const float* __restrict__ bls,
                                              float* __restrict__ mu_out,
                                              float* __restrict__ ls_out) {
    int t = threadIdx.x;
    int wave = t >> 6, lane = t & 63;
    int og = __builtin_amdgcn_readfirstlane(wave | ((int)blockIdx.y << 2)); // 0..7
    int half = og >> 2;
    int co = (og & 3) << 3;
    int node = blockIdx.x * 64 + lane;
    if (node >= N_NODES) return;
    const float* W  = half ? Wls : Wmu;
    const float* bb = half ? bls : bmu;
    float* out      = half ? ls_out : mu_out;

    uint4 p = *(const uint4*)(pml + (size_t)node * 64 + half * 32 + co);
    float acc[8];
    acc[0] = bf2f((unsigned short)(p.x & 0xFFFFu));
    acc[1] = bf2f((unsigned short)(p.x >> 16));
    acc[2] = bf2f((unsigned short)(p.y & 0xFFFFu));
    acc[3] = bf2f((unsigned short)(p.y >> 16));
    acc[4] = bf2f((unsigned short)(p.z & 0xFFFFu));
    acc[5] = bf2f((unsigned short)(p.z >> 16));
    acc[6] = bf2f((unsigned short)(p.w & 0xFFFFu));
    acc[7] = bf2f((unsigned short)(p.w >> 16));
#pragma unroll
    for (int j = 0; j < 8; ++j) acc[j] += bb[co + j];

    const float4* hp = (const float4*)(h2in + (size_t)node * GC_HID);
#pragma unroll
    for (int v = 0; v < 5; ++v) {
        float4 hh = hp[v];
#pragma unroll
        for (int c = 0; c < 4; ++c) {
            float x = (c == 0) ? hh.x : (c == 1) ? hh.y : (c == 2) ? hh.z : hh.w;
            const float* wr = W + (v * 4 + c) * Z_DIM + co;
#pragma unroll
            for (int j = 0; j < 8; ++j) acc[j] = fmaf(x, wr[j], acc[j]);
        }
    }
    float4* op = (float4*)(out + (size_t)node * Z_DIM + co);
    op[0] = make_float4(acc[0], acc[1], acc[2], acc[3]);
    op[1] = make_float4(acc[4], acc[5], acc[6], acc[7]);
}

// reparameterization: z = mu + (1e-4 + exp(0.5*ls)) * eps
__global__ __launch_bounds__(256) void k_z(const float* __restrict__ mu,
                                           const float* __restrict__ ls,
                                           const float* __restrict__ eps,
                                           float* __restrict__ z) {
    int i = blockIdx.x * 256 + threadIdx.x;
    if (i >= N_NODES * Z_DIM / 4) return;
    float4 m = ((const float4*)mu)[i];
    float4 l = ((const float4*)ls)[i];
    float4 e = ((const float4*)eps)[i];
    float4 zz;
    zz.x = m.x + (1e-4f + __expf(0.5f * l.x)) * e.x;
    zz.y = m.y + (1e-4f + __expf(0.5f * l.y)) * e.y;
    zz.z = m.z + (1e-4f + __expf(0.5f * l.z)) * e.z;
    zz.w = m.w + (1e-4f + __expf(0.5f * l.w)) * e.w;
    ((float4*)z)[i] = zz;
}

// decoder stage 1: d = relu(z@Wd1+bd1), thread per node (weights uniform)
__global__ __launch_bounds__(256) void k_decd(const float* __restrict__ z,
                                              const float* __restrict__ Wd1,
                                              const float* __restrict__ bd1,
                                              float* __restrict__ dbuf) {
    int node = blockIdx.x * 256 + threadIdx.x;
    if (node >= N_NODES) return;
    float d[DEC_HID];
#pragma unroll
    for (int j = 0; j < DEC_HID; ++j) d[j] = bd1[j];
    const float4* zp = (const float4*)(z + (size_t)node * Z_DIM);
#pragma unroll
    for (int v = 0; v < Z_DIM / 4; ++v) {
        float4 zz = zp[v];
#pragma unroll
        for (int c = 0; c < 4; ++c) {
            float x = (c == 0) ? zz.x : (c == 1) ? zz.y : (c == 2) ? zz.z : zz.w;
            const float* wr = Wd1 + (v * 4 + c) * DEC_HID;
#pragma unroll
            for (int j = 0; j < DEC_HID; ++j) d[j] = fmaf(x, wr[j], d[j]);
        }
    }
    float4* op = (float4*)(dbuf + (size_t)node * DEC_HID);
#pragma unroll
    for (int v = 0; v < DEC_HID / 4; ++v)
        op[v] = make_float4(fmaxf(d[4*v], 0.f), fmaxf(d[4*v+1], 0.f),
                            fmaxf(d[4*v+2], 0.f), fmaxf(d[4*v+3], 0.f));
}

// decoder stage 2: chunk id forced wave-uniform via readfirstlane; lane = node.
__global__ __launch_bounds__(256) void k_decx(const float* __restrict__ dbuf,
                                              const float* __restrict__ Wd2,
                                              const float* __restrict__ bd2,
                                              float* __restrict__ X) {
    int lane = threadIdx.x & 63;
    int wv   = threadIdx.x >> 6;             // 0..3
    int ch   = __builtin_amdgcn_readfirstlane(((blockIdx.x & 1) << 2) | wv);
    int node = (blockIdx.x >> 1) * 64 + lane;
    if (node >= N_NODES) return;
    int co = ch << 5;
    float o[32];
#pragma unroll
    for (int j = 0; j < 32; ++j) o[j] = bd2[co + j];
    const float4* dp = (const float4*)(dbuf + (size_t)node * DEC_HID);
#pragma unroll
    for (int v = 0; v < DEC_HID / 4; ++v) {
        float4 dd = dp[v];
#pragma unroll
        for (int c = 0; c < 4; ++c) {
            float x = (c == 0) ? dd.x : (c == 1) ? dd.y : (c == 2) ? dd.z : dd.w;
            const float* wr = Wd2 + (v * 4 + c) * D_FEAT + co;
#pragma unroll
            for (int j = 0; j < 32; ++j) o[j] = fmaf(x, wr[j], o[j]);
        }
    }
    float4* xp = (float4*)(X + (size_t)node * D_FEAT + co);
#pragma unroll
    for (int v = 0; v < 8; ++v)
        xp[v] = make_float4(o[4*v], o[4*v+1], o[4*v+2], o[4*v+3]);
}

extern "C" void kernel_launch(void* const* d_in, const int* in_sizes, int n_in,
                              void* d_out, int out_size, void* d_ws, size_t ws_size,
                              hipStream_t stream) {
    const float* nodes = (const float*)d_in[0];
    const int*   snd   = (const int*)d_in[1];
    const int*   rcv   = (const int*)d_in[2];
    const float* eps   = (const float*)d_in[3];
    const float* W1    = (const float*)d_in[4];
    const float* b1    = (const float*)d_in[5];
    const float* W2    = (const float*)d_in[6];
    const float* b2    = (const float*)d_in[7];
    const float* Wmu   = (const float*)d_in[8];
    const float* bmu   = (const float*)d_in[9];
    const float* Wls   = (const float*)d_in[10];
    const float* bls   = (const float*)d_in[11];
    const float* Wd1   = (const float*)d_in[12];
    const float* bd1   = (const float*)d_in[13];
    const float* Wd2   = (const float*)d_in[14];
    const float* bd2   = (const float*)d_in[15];

    char* ws = (char*)d_ws;
    float*          h_pre    = (float*)(ws);
    float*          agg      = (float*)(ws + 8000000);
    float*          dbuf     = (float*)(ws);              // overlays h_pre+agg (dead)
    unsigned*       grec     = (unsigned*)(ws + 16000000);
    unsigned*       rec_r    = (unsigned*)(ws + 28804096);
    unsigned short* pml      = (unsigned short*)(ws + 28804096); // overlays rec_r post-gscat
    unsigned short* srow_r   = (unsigned short*)(ws + 41608192);
    unsigned*       pref_t   = (unsigned*)(ws + 42836720);
    float*          zbuf     = (float*)(ws + 41608192);   // overlays srow_r/pref_t/row_ptr post-gather
    unsigned*       row_ptr  = (unsigned*)(ws + 45287504);
    unsigned*       gtot     = (unsigned*)(ws + 45687508);
    unsigned*       gbase    = (unsigned*)(ws + 45689076);
    float*          rs_s     = (float*)(ws + 45690648);
    unsigned char*  rec_s    = (unsigned char*)(ws + 46090648);
    unsigned short* srow_s   = (unsigned short*)(ws + 49291672);
    float*          Wpack    = (float*)(ws + 50520192);

    float* X      = (float*)d_out;
    float* mu_out = X + (size_t)N_NODES * D_FEAT;
    float* ls_out = mu_out + (size_t)N_NODES * Z_DIM;

    k_wpack<<<256, 96, 0, stream>>>(W1, Wmu, Wls, Wpack);
    k_sort<<<NBLK, 512, 0, stream>>>(snd, rcv, rec_r, rec_s, srow_r, srow_s);
    k_degs<<<SB, 512, 0, stream>>>(rec_s, srow_s, rs_s);
    k_scanB<<<SB, 256, 0, stream>>>(srow_r, pref_t, gtot);
    k_scanG<<<1, 512, 0, stream>>>(gtot, gbase);
    k_gscat<<<NBLK, 256, 0, stream>>>(rec_r, srow_r, pref_t, gbase, grec);
    k_sort2<<<SB, 256, 0, stream>>>(grec, gbase, row_ptr);

    // fused gc1 + encoder nodes-partials (register-blocked GEMM,
    // both operands via LDS; no scalar loads in the hot loop)
    k_gc1f<<<1563, GF_THREADS, 0, stream>>>(nodes, Wpack, b1, rs_s, h_pre, pml);
    k_gather<<<1563, 320, 0, stream>>>(row_ptr, grec, h_pre, agg);
    k_gc2<<<391, 256, 0, stream>>>(agg, W2, b2, rs_s, h_pre);
    k_gather<<<1563, 320, 0, stream>>>(row_ptr, grec, h_pre, agg);

    k_enc2<<<dim3(1563, 2), 256, 0, stream>>>(agg, pml, Wmu, bmu, Wls, bls,
                                              mu_out, ls_out);
    k_z<<<3125, 256, 0, stream>>>(mu_out, ls_out, eps, zbuf);
    k_decd<<<391, 256, 0, stream>>>(zbuf, Wd1, bd1, dbuf);
    k_decx<<<3126, 256, 0, stream>>>(dbuf, Wd2, bd2, X);
}

// Round 23
// 422.841 us; speedup vs baseline: 1.0505x; 1.0505x over previous
//
#include <hip/hip_runtime.h>
#include <math.h>

#define N_NODES 100000
#define N_EDGES 3200000
#define D_FEAT 256
#define GC_HID 20
#define DEC_HID 40
#define Z_DIM 32

#define EPB 2048          // edges per sort block
#define NBLK 1563         // ceil(3.2M / 2048)
#define SB 392            // node buckets of 256 (392*256 = 100352)
#define SBSH 8
#define S2CAP 12288       // per-bucket record cap

// ---------------- ws layout (bytes) ----------------
// h_pre  @ 0           8,000,000
// agg    @ 8,000,000   8,000,000
// dbuf   @ 0          16,000,000   (overlays h_pre+agg when dead)
// grec   @16,000,000  12,804,096
// rec_r  @28,804,096  12,804,096   (pml bf16 [N][64]=12.8MB overlays post-gscat)
// srow_r @41,608,192   1,228,518
// pref_t @42,836,720   2,450,784
// row_ptr@45,287,504     400,004
// gtot   @45,687,508       1,568
// gbase  @45,689,076       1,572
// rs_s   @45,690,648     400,000
// rec_s  @46,090,648   3,201,024
// srow_s @49,291,672   1,228,518
// Wpack  @50,520,192      98,304   end = 50,618,496

__device__ inline unsigned short f2bf(float f) {
    unsigned u = __float_as_uint(f);
    return (unsigned short)((u + 0x7FFFu + ((u >> 16) & 1u)) >> 16);
}
__device__ inline float bf2f(unsigned short h) {
    return __uint_as_float((unsigned)h << 16);
}

// pack node-row weights: Wpack[k][0:20]=W1[k], [24:56]=Wmu[20+k], [56:88]=Wls[20+k]
__global__ __launch_bounds__(96) void k_wpack(const float* __restrict__ W1,
                                              const float* __restrict__ Wmu,
                                              const float* __restrict__ Wls,
                                              float* __restrict__ Wp) {
    int k = blockIdx.x, j = threadIdx.x;
    float v = 0.0f;
    if (j < 20) v = W1[k * GC_HID + j];
    else if (j >= 24 && j < 56) v = Wmu[(GC_HID + k) * Z_DIM + (j - 24)];
    else if (j >= 56 && j < 88) v = Wls[(GC_HID + k) * Z_DIM + (j - 56)];
    Wp[k * 96 + j] = v;
}

// dual block-local counting sort (receiver u32 + sender u8 streams).
// ZERO global atomics (R13: each device-scope atomic = memory-side write).
__global__ __launch_bounds__(512) void k_sort(const int* __restrict__ snd,
                                              const int* __restrict__ rcv,
                                              unsigned* __restrict__ rec_r,
                                              unsigned char* __restrict__ rec_s,
                                              unsigned short* __restrict__ srow_r,
                                              unsigned short* __restrict__ srow_s) {
    __shared__ int es[EPB], er[EPB];
    __shared__ unsigned scan[SB + 1];
    __shared__ unsigned cur[SB];
    __shared__ unsigned sorted[EPB];
    __shared__ unsigned char sorteds[EPB];
    int b = blockIdx.x, t = threadIdx.x;
    int base = b * EPB;
    int cnt = min(EPB, N_EDGES - base);
    for (int i = t; i < cnt; i += 512) { es[i] = snd[base + i]; er[i] = rcv[base + i]; }

    for (int i = t; i < SB + 1; i += 512) scan[i] = 0u;
    __syncthreads();
    for (int i = t; i < cnt; i += 512) atomicAdd(&scan[(er[i] >> SBSH) + 1], 1u);
    __syncthreads();
    for (int off = 1; off < SB + 1; off <<= 1) {
        unsigned v = (t >= off && t < SB + 1) ? scan[t - off] : 0u;
        __syncthreads();
        if (t < SB + 1) scan[t] += v;
        __syncthreads();
    }
    for (int i = t; i < SB + 1; i += 512) srow_r[(size_t)b * (SB + 1) + i] = (unsigned short)scan[i];
    if (t < SB) cur[t] = scan[t];
    __syncthreads();
    for (int i = t; i < cnt; i += 512) {
        int r = er[i];
        unsigned pos = atomicAdd(&cur[r >> SBSH], 1u);
        sorted[pos] = ((unsigned)(r & 255) << 17) | (unsigned)es[i];
    }
    __syncthreads();
    for (int i = t; i < cnt; i += 512) rec_r[(size_t)base + i] = sorted[i];
    __syncthreads();

    for (int i = t; i < SB + 1; i += 512) scan[i] = 0u;
    __syncthreads();
    for (int i = t; i < cnt; i += 512) atomicAdd(&scan[(es[i] >> SBSH) + 1], 1u);
    __syncthreads();
    for (int off = 1; off < SB + 1; off <<= 1) {
        unsigned v = (t >= off && t < SB + 1) ? scan[t - off] : 0u;
        __syncthreads();
        if (t < SB + 1) scan[t] += v;
        __syncthreads();
    }
    for (int i = t; i < SB + 1; i += 512) srow_s[(size_t)b * (SB + 1) + i] = (unsigned short)scan[i];
    if (t < SB) cur[t] = scan[t];
    __syncthreads();
    for (int i = t; i < cnt; i += 512) {
        int s = es[i];
        unsigned pos = atomicAdd(&cur[s >> SBSH], 1u);
        sorteds[pos] = (unsigned char)(s & 255);
    }
    __syncthreads();
    for (int i = t; i < cnt; i += 512) rec_s[(size_t)base + i] = sorteds[i];
}

// sender-degree via per-bucket LDS histogram over sender-sorted runs
__global__ __launch_bounds__(512) void k_degs(const unsigned char* __restrict__ rec_s,
                                              const unsigned short* __restrict__ srow_s,
                                              float* __restrict__ rs_s) {
    __shared__ unsigned h[256];
    int s = blockIdx.x, t = threadIdx.x;
    if (t < 256) h[t] = 0u;
    __syncthreads();
    for (int k = t; k < NBLK; k += 512) {
        const unsigned short* row = srow_s + (size_t)k * (SB + 1);
        unsigned st = row[s], en = row[s + 1];
        const unsigned char* rp = rec_s + (size_t)k * EPB;
        for (unsigned i = st; i < en; ++i) atomicAdd(&h[rp[i]], 1u);
    }
    __syncthreads();
    if (t < 256) {
        int n = (s << SBSH) + t;
        if (n < N_NODES) rs_s[n] = rsqrtf(fmaxf((float)h[t], 1.0f));
    }
}

// per-bucket prefix over block segments: pref_t[s][k], totals gtot[s]
__global__ __launch_bounds__(256) void k_scanB(const unsigned short* __restrict__ srow_r,
                                               unsigned* __restrict__ pref_t,
                                               unsigned* __restrict__ gtot) {
    __shared__ unsigned buf[256];
    int s = blockIdx.x, t = threadIdx.x;
    unsigned run = 0;
    for (int k0 = 0; k0 < NBLK; k0 += 256) {
        int k = k0 + t;
        unsigned v = 0;
        if (k < NBLK) {
            const unsigned short* row = srow_r + (size_t)k * (SB + 1);
            v = (unsigned)row[s + 1] - (unsigned)row[s];
        }
        buf[t] = v;
        __syncthreads();
        for (int off = 1; off < 256; off <<= 1) {
            unsigned x = (t >= off) ? buf[t - off] : 0u;
            __syncthreads();
            buf[t] += x;
            __syncthreads();
        }
        if (k < NBLK) pref_t[(size_t)s * NBLK + k] = run + (buf[t] - v);
        unsigned tot = buf[255];
        __syncthreads();
        run += tot;
    }
    if (t == 0) gtot[s] = run;
}

// exclusive scan of bucket totals -> gbase[SB+1]
__global__ __launch_bounds__(512) void k_scanG(const unsigned* __restrict__ gtot,
                                               unsigned* __restrict__ gbase) {
    __shared__ unsigned buf[SB];
    int t = threadIdx.x;
    if (t < SB) buf[t] = gtot[t];
    __syncthreads();
    for (int off = 1; off < SB; off <<= 1) {
        unsigned x = (t >= off && t < SB) ? buf[t - off] : 0u;
        __syncthreads();
        if (t < SB) buf[t] += x;
        __syncthreads();
    }
    if (t < SB) gbase[t + 1] = buf[t];
    if (t == 0) gbase[0] = 0u;
}

// scatter block-sorted records to global bucket-sorted order
__global__ __launch_bounds__(256) void k_gscat(const unsigned* __restrict__ rec_r,
                                               const unsigned short* __restrict__ srow_r,
                                               const unsigned* __restrict__ pref_t,
                                               const unsigned* __restrict__ gbase,
                                               unsigned* __restrict__ grec) {
    __shared__ unsigned recs[EPB];
    __shared__ unsigned short srow[SB + 1];
    int b = blockIdx.x, t = threadIdx.x;
    int base = b * EPB;
    int cnt = min(EPB, N_EDGES - base);
    for (int i = t; i < cnt; i += 256) recs[i] = rec_r[(size_t)base + i];
    for (int i = t; i < SB + 1; i += 256) srow[i] = srow_r[(size_t)b * (SB + 1) + i];
    __syncthreads();
    for (int s = t; s < SB; s += 256) {
        unsigned lo = srow[s], hi = srow[s + 1];
        if (lo == hi) continue;
        unsigned dst = gbase[s] + pref_t[(size_t)s * NBLK + b];
        for (unsigned i = lo; i < hi; ++i) grec[dst + (i - lo)] = recs[i];
    }
}

// within-bucket counting sort by local receiver (in-place) + CSR row_ptr
__global__ __launch_bounds__(256) void k_sort2(unsigned* __restrict__ grec,
                                               const unsigned* __restrict__ gbase,
                                               unsigned* __restrict__ row_ptr) {
    __shared__ unsigned recs[S2CAP];     // 48 KB
    __shared__ unsigned hist[256];
    __shared__ unsigned scan[256];
    __shared__ unsigned cur[256];
    int s = blockIdx.x, t = threadIdx.x;
    unsigned lo = gbase[s], hi = gbase[s + 1];
    unsigned cnt = min(hi - lo, (unsigned)S2CAP);
    for (unsigned i = t; i < cnt; i += 256) recs[i] = grec[lo + i];
    hist[t] = 0u;
    __syncthreads();
    for (unsigned i = t; i < cnt; i += 256) atomicAdd(&hist[recs[i] >> 17], 1u);
    __syncthreads();
    unsigned v = hist[t];
    scan[t] = v;
    __syncthreads();
    for (int off = 1; off < 256; off <<= 1) {
        unsigned x = (t >= off) ? scan[t - off] : 0u;
        __syncthreads();
        scan[t] += x;
        __syncthreads();
    }
    unsigned excl = scan[t] - v;
    {
        int n = (s << SBSH) + t;
        if (n <= N_NODES) row_ptr[n] = lo + excl;
    }
    cur[t] = excl;
    __syncthreads();
    for (unsigned i = t; i < cnt; i += 256) {
        unsigned rec = recs[i];
        unsigned pos = atomicAdd(&cur[rec >> 17], 1u);
        grec[lo + pos] = rec & 0x1FFFFu;
    }
}

// pure CSR gather: 5 lanes per node, one float4 each; zero atomics.
__global__ __launch_bounds__(320) void k_gather(const unsigned* __restrict__ row_ptr,
                                                const unsigned* __restrict__ grec,
                                                const float* __restrict__ src,
                                                float* __restrict__ dst) {
    int gid = blockIdx.x * 320 + threadIdx.x;
    int node = gid / 5, q = gid % 5;
    if (node >= N_NODES) return;
    unsigned lo = row_ptr[node], hi = row_ptr[node + 1];
    float4 a0 = make_float4(0.f, 0.f, 0.f, 0.f);
    float4 a1 = make_float4(0.f, 0.f, 0.f, 0.f);
    float4 a2 = make_float4(0.f, 0.f, 0.f, 0.f);
    float4 a3 = make_float4(0.f, 0.f, 0.f, 0.f);
    unsigned e = lo;
    for (; e + 4 <= hi; e += 4) {
        unsigned s0 = grec[e], s1 = grec[e + 1], s2 = grec[e + 2], s3 = grec[e + 3];
        float4 v0 = ((const float4*)src)[s0 * 5 + q];
        float4 v1 = ((const float4*)src)[s1 * 5 + q];
        float4 v2 = ((const float4*)src)[s2 * 5 + q];
        float4 v3 = ((const float4*)src)[s3 * 5 + q];
        a0.x += v0.x; a0.y += v0.y; a0.z += v0.z; a0.w += v0.w;
        a1.x += v1.x; a1.y += v1.y; a1.z += v1.z; a1.w += v1.w;
        a2.x += v2.x; a2.y += v2.y; a2.z += v2.z; a2.w += v2.w;
        a3.x += v3.x; a3.y += v3.y; a3.z += v3.z; a3.w += v3.w;
    }
    for (; e < hi; ++e) {
        unsigned s0 = grec[e];
        float4 v0 = ((const float4*)src)[s0 * 5 + q];
        a0.x += v0.x; a0.y += v0.y; a0.z += v0.z; a0.w += v0.w;
    }
    a0.x += a1.x + a2.x + a3.x;
    a0.y += a1.y + a2.y + a3.y;
    a0.z += a1.z + a2.z + a3.z;
    a0.w += a1.w + a2.w + a3.w;
    float sc = rsqrtf(fmaxf((float)(hi - lo), 1.0f));
    a0.x *= sc; a0.y *= sc; a0.z *= sc; a0.w *= sc;
    ((float4*)dst)[node * 5 + q] = a0;
}

// FUSED gc1 + encoder-partials (R21 version -- local optimum at ~105us):
// 256 thr (4 waves = 4 output groups), 64 nodes/block, 1563 blocks.
// Packed weights (one K$-resident 384B row per k, s_load broadcast),
// double-buffered x-tile with register prefetch, 0 bank conflicts.
__global__ __launch_bounds__(256) void k_gc1f(const float* __restrict__ nodes,
                                              const float* __restrict__ Wp,
                                              const float* __restrict__ b1,
                                              const float* __restrict__ rs_s,
                                              float* __restrict__ h_pre,
                                              unsigned short* __restrict__ pml) {
    __shared__ float tile[2][64 * 33];     // 16,896 B
    float* gb = &tile[0][0];               // aliased after last buf0 use
    int t = threadIdx.x;
    int g = __builtin_amdgcn_readfirstlane(t >> 6);  // 0..3: packed-col group
    int lane = t & 63;
    int n0 = blockIdx.x * 64;
    int node = n0 + lane;

    // stage chunk 0 (k 0..32): 512 float4, 256 threads -> 2 each
    {
        int idx = t;
#pragma unroll
        for (int r = 0; r < 2; ++r, idx += 256) {
            int rr = idx >> 3, c4 = idx & 7;
            int gn = n0 + rr;
            float4 v = (gn < N_NODES)
                ? ((const float4*)nodes)[(size_t)gn * 64 + c4]
                : make_float4(0.f, 0.f, 0.f, 0.f);
            float* dst = &tile[0][rr * 33 + c4 * 4];
            dst[0] = v.x; dst[1] = v.y; dst[2] = v.z; dst[3] = v.w;
        }
    }
    __syncthreads();

    float acc[24];
#pragma unroll
    for (int j = 0; j < 24; ++j) acc[j] = 0.0f;

    for (int c = 0; c < 8; ++c) {
        float4 p0, p1;
        if (c < 7) {
            int idx = t, rr = idx >> 3, c4 = idx & 7, gn = n0 + rr;
            p0 = (gn < N_NODES)
                ? ((const float4*)nodes)[(size_t)gn * 64 + (c + 1) * 8 + c4]
                : make_float4(0.f, 0.f, 0.f, 0.f);
            idx = t + 256; rr = idx >> 3; c4 = idx & 7; gn = n0 + rr;
            p1 = (gn < N_NODES)
                ? ((const float4*)nodes)[(size_t)gn * 64 + (c + 1) * 8 + c4]
                : make_float4(0.f, 0.f, 0.f, 0.f);
        }
        const float* trow  = &tile[c & 1][lane * 33];
        const float* wbase = Wp + (size_t)(c * 32) * 96 + g * 24;
#pragma unroll 4
        for (int kk = 0; kk < 32; ++kk) {
            float x = trow[kk];
            const float* wr = wbase + kk * 96;
#pragma unroll
            for (int j = 0; j < 24; ++j) acc[j] = fmaf(x, wr[j], acc[j]);
        }
        if (c < 7) {
            int idx = t, rr = idx >> 3, c4 = idx & 7;
            float* dst = &tile[(c + 1) & 1][rr * 33 + c4 * 4];
            dst[0] = p0.x; dst[1] = p0.y; dst[2] = p0.z; dst[3] = p0.w;
            idx = t + 256; rr = idx >> 3; c4 = idx & 7;
            dst = &tile[(c + 1) & 1][rr * 33 + c4 * 4];
            dst[0] = p1.x; dst[1] = p1.y; dst[2] = p1.z; dst[3] = p1.w;
        }
        __syncthreads();
    }

    if (node < N_NODES) {
        if (g == 0) {
#pragma unroll
            for (int j = 0; j < GC_HID; ++j) gb[lane * 21 + j] = acc[j] + b1[j];
        } else {
            int base = (g - 1) * 24;
            unsigned short* pp = pml + (size_t)node * 64 + base;
            uint4 q0, q1, q2;
            q0.x = (unsigned)f2bf(acc[0]) | ((unsigned)f2bf(acc[1]) << 16);
            q0.y = (unsigned)f2bf(acc[2]) | ((unsigned)f2bf(acc[3]) << 16);
            q0.z = (unsigned)f2bf(acc[4]) | ((unsigned)f2bf(acc[5]) << 16);
            q0.w = (unsigned)f2bf(acc[6]) | ((unsigned)f2bf(acc[7]) << 16);
            q1.x = (unsigned)f2bf(acc[8]) | ((unsigned)f2bf(acc[9]) << 16);
            q1.y = (unsigned)f2bf(acc[10]) | ((unsigned)f2bf(acc[11]) << 16);
            q1.z = (unsigned)f2bf(acc[12]) | ((unsigned)f2bf(acc[13]) << 16);
            q1.w = (unsigned)f2bf(acc[14]) | ((unsigned)f2bf(acc[15]) << 16);
            q2.x = (unsigned)f2bf(acc[16]) | ((unsigned)f2bf(acc[17]) << 16);
            q2.y = (unsigned)f2bf(acc[18]) | ((unsigned)f2bf(acc[19]) << 16);
            q2.z = (unsigned)f2bf(acc[20]) | ((unsigned)f2bf(acc[21]) << 16);
            q2.w = (unsigned)f2bf(acc[22]) | ((unsigned)f2bf(acc[23]) << 16);
            ((uint4*)pp)[0] = q0;
            ((uint4*)pp)[1] = q1;
            if (g != 3) ((uint4*)pp)[2] = q2;
        }
    }
    __syncthreads();
    if (t < 64) {
        int nn = n0 + t;
        if (nn < N_NODES) {
            float v[GC_HID];
            float mx = -1e30f;
#pragma unroll
            for (int j = 0; j < GC_HID; ++j) {
                v[j] = fmaxf(gb[t * 21 + j], 0.0f);
                mx = fmaxf(mx, v[j]);
            }
            float s = 0.0f;
#pragma unroll
            for (int j = 0; j < GC_HID; ++j) {
                v[j] = __expf(v[j] - mx);
                s += v[j];
            }
            float inv = rs_s[nn] / s;
#pragma unroll
            for (int j = 0; j < GC_HID; ++j) v[j] *= inv;
            float4* o = (float4*)&h_pre[(size_t)nn * GC_HID];
            o[0] = make_float4(v[0],  v[1],  v[2],  v[3]);
            o[1] = make_float4(v[4],  v[5],  v[6],  v[7]);
            o[2] = make_float4(v[8],  v[9],  v[10], v[11]);
            o[3] = make_float4(v[12], v[13], v[14], v[15]);
            o[4] = make_float4(v[16], v[17], v[18], v[19]);
        }
    }
}

// GC layer 2 transform: h2_pre = softmax(relu(h1@W2+b2)) * rs_s
__global__ __launch_bounds__(256) void k_gc2(const float* __restrict__ h1in,
                                             const float* __restrict__ W2,
                                             const float* __restrict__ b2,
                                             const float* __restrict__ rs_s,
                                             float* __restrict__ h2_pre) {
    __shared__ float Wsh[GC_HID * GC_HID];
    __shared__ float bsh[GC_HID];
    int tid = threadIdx.x;
    if (tid < GC_HID * GC_HID) Wsh[tid] = W2[tid];
    if (tid < GC_HID) bsh[tid] = b2[tid];
    __syncthreads();
    int node = blockIdx.x * 256 + tid;
    if (node >= N_NODES) return;
    const float4* ap = (const float4*)&h1in[node * GC_HID];
    float4 a0 = ap[0], a1 = ap[1], a2 = ap[2], a3 = ap[3], a4 = ap[4];
    float h1[GC_HID] = {a0.x,a0.y,a0.z,a0.w, a1.x,a1.y,a1.z,a1.w,
                        a2.x,a2.y,a2.z,a2.w, a3.x,a3.y,a3.z,a3.w,
                        a4.x,a4.y,a4.z,a4.w};
    float t[GC_HID];
#pragma unroll
    for (int j = 0; j < GC_HID; ++j) t[j] = bsh[j];
#pragma unroll
    for (int i = 0; i < GC_HID; ++i) {
        float x = h1[i];
#pragma unroll
        for (int j = 0; j < GC_HID; ++j) t[j] = fmaf(x, Wsh[i * GC_HID + j], t[j]);
    }
    float mx = -1e30f;
#pragma unroll
    for (int j = 0; j < GC_HID; ++j) { t[j] = fmaxf(t[j], 0.0f); mx = fmaxf(mx, t[j]); }
    float s = 0.0f;
#pragma unroll
    for (int j = 0; j < GC_HID; ++j) { t[j] = __expf(t[j] - mx); s += t[j]; }
    float inv = rs_s[node] / s;
#pragma unroll
    for (int j = 0; j < GC_HID; ++j) t[j] *= inv;
    float4* o = (float4*)&h2_pre[node * GC_HID];
    o[0] = make_float4(t[0],  t[1],  t[2],  t[3]);
    o[1] = make_float4(t[4],  t[5],  t[6],  t[7]);
    o[2] = make_float4(t[8],  t[9],  t[10], t[11]);
    o[3] = make_float4(t[12], t[13], t[14], t[15]);
    o[4] = make_float4(t[16], t[17], t[18], t[19]);
}

// encoder finish: mu/ls = bias + pml + h2 @ W[0:20]. Octet split,
// grid (1563, 2), block 256 = 4 waves x 64 nodes.
__global__ __launch_bounds__(256) void k_enc2(const float* __restrict__ h2in,
                                              const unsigned short* __restrict__ pml,
                                              const float* __restrict__ Wmu,
                                              const float* __restrict__ bmu,
                                              const float* __restrict__ Wls,
                                              const float* __restrict__ bls,
                                              float* __restrict__ mu_out,
                                              float* __restrict__ ls_out) {
    int t = threadIdx.x;
    int wave = t >> 6, lane = t & 63;
    int og = __builtin_amdgcn_readfirstlane(wave | ((int)blockIdx.y << 2)); // 0..7
    int half = og >> 2;
    int co = (og & 3) << 3;
    int node = blockIdx.x * 64 + lane;
    if (node >= N_NODES) return;
    const float* W  = half ? Wls : Wmu;
    const float* bb = half ? bls : bmu;
    float* out      = half ? ls_out : mu_out;

    uint4 p = *(const uint4*)(pml + (size_t)node * 64 + half * 32 + co);
    float acc[8];
    acc[0] = bf2f((unsigned short)(p.x & 0xFFFFu));
    acc[1] = bf2f((unsigned short)(p.x >> 16));
    acc[2] = bf2f((unsigned short)(p.y & 0xFFFFu));
    acc[3] = bf2f((unsigned short)(p.y >> 16));
    acc[4] = bf2f((unsigned short)(p.z & 0xFFFFu));
    acc[5] = bf2f((unsigned short)(p.z >> 16));
    acc[6] = bf2f((unsigned short)(p.w & 0xFFFFu));
    acc[7] = bf2f((unsigned short)(p.w >> 16));
#pragma unroll
    for (int j = 0; j < 8; ++j) acc[j] += bb[co + j];

    const float4* hp = (const float4*)(h2in + (size_t)node * GC_HID);
#pragma unroll
    for (int v = 0; v < 5; ++v) {
        float4 hh = hp[v];
#pragma unroll
        for (int c = 0; c < 4; ++c) {
            float x = (c == 0) ? hh.x : (c == 1) ? hh.y : (c == 2) ? hh.z : hh.w;
            const float* wr = W + (v * 4 + c) * Z_DIM + co;
#pragma unroll
            for (int j = 0; j < 8; ++j) acc[j] = fmaf(x, wr[j], acc[j]);
        }
    }
    float4* op = (float4*)(out + (size_t)node * Z_DIM + co);
    op[0] = make_float4(acc[0], acc[1], acc[2], acc[3]);
    op[1] = make_float4(acc[4], acc[5], acc[6], acc[7]);
}

// decoder stage 1 (k_z fused): z = mu + (1e-4+exp(0.5*ls))*eps computed
// in registers; d = relu(z@Wd1+bd1). Thread per node, weights uniform.
__global__ __launch_bounds__(256) void k_decd(const float* __restrict__ mu,
                                              const float* __restrict__ ls,
                                              const float* __restrict__ eps,
                                              const float* __restrict__ Wd1,
                                              const float* __restrict__ bd1,
                                              float* __restrict__ dbuf) {
    int node = blockIdx.x * 256 + threadIdx.x;
    if (node >= N_NODES) return;
    float d[DEC_HID];
#pragma unroll
    for (int j = 0; j < DEC_HID; ++j) d[j] = bd1[j];
    const float4* mp = (const float4*)(mu + (size_t)node * Z_DIM);
    const float4* lp = (const float4*)(ls + (size_t)node * Z_DIM);
    const float4* ep = (const float4*)(eps + (size_t)node * Z_DIM);
#pragma unroll
    for (int v = 0; v < Z_DIM / 4; ++v) {
        float4 m = mp[v], l = lp[v], e = ep[v];
        float4 zz;
        zz.x = m.x + (1e-4f + __expf(0.5f * l.x)) * e.x;
        zz.y = m.y + (1e-4f + __expf(0.5f * l.y)) * e.y;
        zz.z = m.z + (1e-4f + __expf(0.5f * l.z)) * e.z;
        zz.w = m.w + (1e-4f + __expf(0.5f * l.w)) * e.w;
#pragma unroll
        for (int c = 0; c < 4; ++c) {
            float x = (c == 0) ? zz.x : (c == 1) ? zz.y : (c == 2) ? zz.z : zz.w;
            const float* wr = Wd1 + (v * 4 + c) * DEC_HID;
#pragma unroll
            for (int j = 0; j < DEC_HID; ++j) d[j] = fmaf(x, wr[j], d[j]);
        }
    }
    float4* op = (float4*)(dbuf + (size_t)node * DEC_HID);
#pragma unroll
    for (int v = 0; v < DEC_HID / 4; ++v)
        op[v] = make_float4(fmaxf(d[4*v], 0.f), fmaxf(d[4*v+1], 0.f),
                            fmaxf(d[4*v+2], 0.f), fmaxf(d[4*v+3], 0.f));
}

// decoder stage 2: chunk id forced wave-uniform via readfirstlane; lane = node.
__global__ __launch_bounds__(256) void k_decx(const float* __restrict__ dbuf,
                                              const float* __restrict__ Wd2,
                                              const float* __restrict__ bd2,
                                              float* __restrict__ X) {
    int lane = threadIdx.x & 63;
    int wv   = threadIdx.x >> 6;             // 0..3
    int ch   = __builtin_amdgcn_readfirstlane(((blockIdx.x & 1) << 2) | wv);
    int node = (blockIdx.x >> 1) * 64 + lane;
    if (node >= N_NODES) return;
    int co = ch << 5;
    float o[32];
#pragma unroll
    for (int j = 0; j < 32; ++j) o[j] = bd2[co + j];
    const float4* dp = (const float4*)(dbuf + (size_t)node * DEC_HID);
#pragma unroll
    for (int v = 0; v < DEC_HID / 4; ++v) {
        float4 dd = dp[v];
#pragma unroll
        for (int c = 0; c < 4; ++c) {
            float x = (c == 0) ? dd.x : (c == 1) ? dd.y : (c == 2) ? dd.z : dd.w;
            const float* wr = Wd2 + (v * 4 + c) * D_FEAT + co;
#pragma unroll
            for (int j = 0; j < 32; ++j) o[j] = fmaf(x, wr[j], o[j]);
        }
    }
    float4* xp = (float4*)(X + (size_t)node * D_FEAT + co);
#pragma unroll
    for (int v = 0; v < 8; ++v)
        xp[v] = make_float4(o[4*v], o[4*v+1], o[4*v+2], o[4*v+3]);
}

extern "C" void kernel_launch(void* const* d_in, const int* in_sizes, int n_in,
                              void* d_out, int out_size, void* d_ws, size_t ws_size,
                              hipStream_t stream) {
    const float* nodes = (const float*)d_in[0];
    const int*   snd   = (const int*)d_in[1];
    const int*   rcv   = (const int*)d_in[2];
    const float* eps   = (const float*)d_in[3];
    const float* W1    = (const float*)d_in[4];
    const float* b1    = (const float*)d_in[5];
    const float* W2    = (const float*)d_in[6];
    const float* b2    = (const float*)d_in[7];
    const float* Wmu   = (const float*)d_in[8];
    const float* bmu   = (const float*)d_in[9];
    const float* Wls   = (const float*)d_in[10];
    const float* bls   = (const float*)d_in[11];
    const float* Wd1   = (const float*)d_in[12];
    const float* bd1   = (const float*)d_in[13];
    const float* Wd2   = (const float*)d_in[14];
    const float* bd2   = (const float*)d_in[15];

    char* ws = (char*)d_ws;
    float*          h_pre    = (float*)(ws);
    float*          agg      = (float*)(ws + 8000000);
    float*          dbuf     = (float*)(ws);              // overlays h_pre+agg (dead)
    unsigned*       grec     = (unsigned*)(ws + 16000000);
    unsigned*       rec_r    = (unsigned*)(ws + 28804096);
    unsigned short* pml      = (unsigned short*)(ws + 28804096); // overlays rec_r post-gscat
    unsigned short* srow_r   = (unsigned short*)(ws + 41608192);
    unsigned*       pref_t   = (unsigned*)(ws + 42836720);
    unsigned*       row_ptr  = (unsigned*)(ws + 45287504);
    unsigned*       gtot     = (unsigned*)(ws + 45687508);
    unsigned*       gbase    = (unsigned*)(ws + 45689076);
    float*          rs_s     = (float*)(ws + 45690648);
    unsigned char*  rec_s    = (unsigned char*)(ws + 46090648);
    unsigned short* srow_s   = (unsigned short*)(ws + 49291672);
    float*          Wpack    = (float*)(ws + 50520192);

    float* X      = (float*)d_out;
    float* mu_out = X + (size_t)N_NODES * D_FEAT;
    float* ls_out = mu_out + (size_t)N_NODES * Z_DIM;

    k_wpack<<<256, 96, 0, stream>>>(W1, Wmu, Wls, Wpack);
    k_sort<<<NBLK, 512, 0, stream>>>(snd, rcv, rec_r, rec_s, srow_r, srow_s);
    k_degs<<<SB, 512, 0, stream>>>(rec_s, srow_s, rs_s);
    k_scanB<<<SB, 256, 0, stream>>>(srow_r, pref_t, gtot);
    k_scanG<<<1, 512, 0, stream>>>(gtot, gbase);
    k_gscat<<<NBLK, 256, 0, stream>>>(rec_r, srow_r, pref_t, gbase, grec);
    k_sort2<<<SB, 256, 0, stream>>>(grec, gbase, row_ptr);

    k_gc1f<<<1563, 256, 0, stream>>>(nodes, Wpack, b1, rs_s, h_pre, pml);
    k_gather<<<1563, 320, 0, stream>>>(row_ptr, grec, h_pre, agg);
    k_gc2<<<391, 256, 0, stream>>>(agg, W2, b2, rs_s, h_pre);
    k_gather<<<1563, 320, 0, stream>>>(row_ptr, grec, h_pre, agg);

    k_enc2<<<dim3(1563, 2), 256, 0, stream>>>(agg, pml, Wmu, bmu, Wls, bls,
                                              mu_out, ls_out);
    k_decd<<<391, 256, 0, stream>>>(mu_out, ls_out, eps, Wd1, bd1, dbuf);
    k_decx<<<3126, 256, 0, stream>>>(dbuf, Wd2, bd2, X);
}

// Round 24
// 417.824 us; speedup vs baseline: 1.0631x; 1.0120x over previous
//
#include <hip/hip_runtime.h>
#include <math.h>

#define N_NODES 100000
#define N_EDGES 3200000
#define D_FEAT 256
#define GC_HID 20
#define DEC_HID 40
#define Z_DIM 32

#define EPB 2048          // edges per sort block
#define NBLK 1563         // ceil(3.2M / 2048)
#define SB 392            // node buckets of 256 (392*256 = 100352)
#define SBSH 8
#define S2CAP 12288       // per-bucket record cap

// ---------------- ws layout (bytes) ----------------
// h_pre  @ 0           8,000,000
// agg    @ 8,000,000   8,000,000
// dbuf   @ 0          16,000,000   (overlays h_pre+agg when dead)
// grec   @16,000,000  12,804,096
// rec_r  @28,804,096  12,804,096   (pml bf16 [N][64]=12.8MB overlays post-gscat)
// srow_r @41,608,192   1,228,518
// pref_t @42,836,720   2,450,784
// row_ptr@45,287,504     400,004
// gtot   @45,687,508       1,568
// gbase  @45,689,076       1,572
// rs_s   @45,690,648     400,000
// rec_s  @46,090,648   3,201,024
// srow_s @49,291,672   1,228,518
// Wpack  @50,520,192      98,304   end = 50,618,496

__device__ inline unsigned short f2bf(float f) {
    unsigned u = __float_as_uint(f);
    return (unsigned short)((u + 0x7FFFu + ((u >> 16) & 1u)) >> 16);
}
__device__ inline float bf2f(unsigned short h) {
    return __uint_as_float((unsigned)h << 16);
}

// pack node-row weights: Wpack[k][0:20]=W1[k], [24:56]=Wmu[20+k], [56:88]=Wls[20+k]
__global__ __launch_bounds__(96) void k_wpack(const float* __restrict__ W1,
                                              const float* __restrict__ Wmu,
                                              const float* __restrict__ Wls,
                                              float* __restrict__ Wp) {
    int k = blockIdx.x, j = threadIdx.x;
    float v = 0.0f;
    if (j < 20) v = W1[k * GC_HID + j];
    else if (j >= 24 && j < 56) v = Wmu[(GC_HID + k) * Z_DIM + (j - 24)];
    else if (j >= 56 && j < 88) v = Wls[(GC_HID + k) * Z_DIM + (j - 56)];
    Wp[k * 96 + j] = v;
}

// dual block-local counting sort (receiver u32 + sender u8 streams).
// ZERO global atomics (R13: each device-scope atomic = memory-side write).
__global__ __launch_bounds__(512) void k_sort(const int* __restrict__ snd,
                                              const int* __restrict__ rcv,
                                              unsigned* __restrict__ rec_r,
                                              unsigned char* __restrict__ rec_s,
                                              unsigned short* __restrict__ srow_r,
                                              unsigned short* __restrict__ srow_s) {
    __shared__ int es[EPB], er[EPB];
    __shared__ unsigned scan[SB + 1];
    __shared__ unsigned cur[SB];
    __shared__ unsigned sorted[EPB];
    __shared__ unsigned char sorteds[EPB];
    int b = blockIdx.x, t = threadIdx.x;
    int base = b * EPB;
    int cnt = min(EPB, N_EDGES - base);
    for (int i = t; i < cnt; i += 512) { es[i] = snd[base + i]; er[i] = rcv[base + i]; }

    for (int i = t; i < SB + 1; i += 512) scan[i] = 0u;
    __syncthreads();
    for (int i = t; i < cnt; i += 512) atomicAdd(&scan[(er[i] >> SBSH) + 1], 1u);
    __syncthreads();
    for (int off = 1; off < SB + 1; off <<= 1) {
        unsigned v = (t >= off && t < SB + 1) ? scan[t - off] : 0u;
        __syncthreads();
        if (t < SB + 1) scan[t] += v;
        __syncthreads();
    }
    for (int i = t; i < SB + 1; i += 512) srow_r[(size_t)b * (SB + 1) + i] = (unsigned short)scan[i];
    if (t < SB) cur[t] = scan[t];
    __syncthreads();
    for (int i = t; i < cnt; i += 512) {
        int r = er[i];
        unsigned pos = atomicAdd(&cur[r >> SBSH], 1u);
        sorted[pos] = ((unsigned)(r & 255) << 17) | (unsigned)es[i];
    }
    __syncthreads();
    for (int i = t; i < cnt; i += 512) rec_r[(size_t)base + i] = sorted[i];
    __syncthreads();

    for (int i = t; i < SB + 1; i += 512) scan[i] = 0u;
    __syncthreads();
    for (int i = t; i < cnt; i += 512) atomicAdd(&scan[(es[i] >> SBSH) + 1], 1u);
    __syncthreads();
    for (int off = 1; off < SB + 1; off <<= 1) {
        unsigned v = (t >= off && t < SB + 1) ? scan[t - off] : 0u;
        __syncthreads();
        if (t < SB + 1) scan[t] += v;
        __syncthreads();
    }
    for (int i = t; i < SB + 1; i += 512) srow_s[(size_t)b * (SB + 1) + i] = (unsigned short)scan[i];
    if (t < SB) cur[t] = scan[t];
    __syncthreads();
    for (int i = t; i < cnt; i += 512) {
        int s = es[i];
        unsigned pos = atomicAdd(&cur[s >> SBSH], 1u);
        sorteds[pos] = (unsigned char)(s & 255);
    }
    __syncthreads();
    for (int i = t; i < cnt; i += 512) rec_s[(size_t)base + i] = sorteds[i];
}

// sender-degree via per-bucket LDS histogram over sender-sorted runs
__global__ __launch_bounds__(512) void k_degs(const unsigned char* __restrict__ rec_s,
                                              const unsigned short* __restrict__ srow_s,
                                              float* __restrict__ rs_s) {
    __shared__ unsigned h[256];
    int s = blockIdx.x, t = threadIdx.x;
    if (t < 256) h[t] = 0u;
    __syncthreads();
    for (int k = t; k < NBLK; k += 512) {
        const unsigned short* row = srow_s + (size_t)k * (SB + 1);
        unsigned st = row[s], en = row[s + 1];
        const unsigned char* rp = rec_s + (size_t)k * EPB;
        for (unsigned i = st; i < en; ++i) atomicAdd(&h[rp[i]], 1u);
    }
    __syncthreads();
    if (t < 256) {
        int n = (s << SBSH) + t;
        if (n < N_NODES) rs_s[n] = rsqrtf(fmaxf((float)h[t], 1.0f));
    }
}

// per-bucket prefix over block segments: pref_t[s][k], totals gtot[s]
__global__ __launch_bounds__(256) void k_scanB(const unsigned short* __restrict__ srow_r,
                                               unsigned* __restrict__ pref_t,
                                               unsigned* __restrict__ gtot) {
    __shared__ unsigned buf[256];
    int s = blockIdx.x, t = threadIdx.x;
    unsigned run = 0;
    for (int k0 = 0; k0 < NBLK; k0 += 256) {
        int k = k0 + t;
        unsigned v = 0;
        if (k < NBLK) {
            const unsigned short* row = srow_r + (size_t)k * (SB + 1);
            v = (unsigned)row[s + 1] - (unsigned)row[s];
        }
        buf[t] = v;
        __syncthreads();
        for (int off = 1; off < 256; off <<= 1) {
            unsigned x = (t >= off) ? buf[t - off] : 0u;
            __syncthreads();
            buf[t] += x;
            __syncthreads();
        }
        if (k < NBLK) pref_t[(size_t)s * NBLK + k] = run + (buf[t] - v);
        unsigned tot = buf[255];
        __syncthreads();
        run += tot;
    }
    if (t == 0) gtot[s] = run;
}

// exclusive scan of bucket totals -> gbase[SB+1]
__global__ __launch_bounds__(512) void k_scanG(const unsigned* __restrict__ gtot,
                                               unsigned* __restrict__ gbase) {
    __shared__ unsigned buf[SB];
    int t = threadIdx.x;
    if (t < SB) buf[t] = gtot[t];
    __syncthreads();
    for (int off = 1; off < SB; off <<= 1) {
        unsigned x = (t >= off && t < SB) ? buf[t - off] : 0u;
        __syncthreads();
        if (t < SB) buf[t] += x;
        __syncthreads();
    }
    if (t < SB) gbase[t + 1] = buf[t];
    if (t == 0) gbase[0] = 0u;
}

// scatter block-sorted records to global bucket-sorted order
__global__ __launch_bounds__(256) void k_gscat(const unsigned* __restrict__ rec_r,
                                               const unsigned short* __restrict__ srow_r,
                                               const unsigned* __restrict__ pref_t,
                                               const unsigned* __restrict__ gbase,
                                               unsigned* __restrict__ grec) {
    __shared__ unsigned recs[EPB];
    __shared__ unsigned short srow[SB + 1];
    int b = blockIdx.x, t = threadIdx.x;
    int base = b * EPB;
    int cnt = min(EPB, N_EDGES - base);
    for (int i = t; i < cnt; i += 256) recs[i] = rec_r[(size_t)base + i];
    for (int i = t; i < SB + 1; i += 256) srow[i] = srow_r[(size_t)b * (SB + 1) + i];
    __syncthreads();
    for (int s = t; s < SB; s += 256) {
        unsigned lo = srow[s], hi = srow[s + 1];
        if (lo == hi) continue;
        unsigned dst = gbase[s] + pref_t[(size_t)s * NBLK + b];
        for (unsigned i = lo; i < hi; ++i) grec[dst + (i - lo)] = recs[i];
    }
}

// within-bucket counting sort by local receiver (in-place) + CSR row_ptr
__global__ __launch_bounds__(256) void k_sort2(unsigned* __restrict__ grec,
                                               const unsigned* __restrict__ gbase,
                                               unsigned* __restrict__ row_ptr) {
    __shared__ unsigned recs[S2CAP];     // 48 KB
    __shared__ unsigned hist[256];
    __shared__ unsigned scan[256];
    __shared__ unsigned cur[256];
    int s = blockIdx.x, t = threadIdx.x;
    unsigned lo = gbase[s], hi = gbase[s + 1];
    unsigned cnt = min(hi - lo, (unsigned)S2CAP);
    for (unsigned i = t; i < cnt; i += 256) recs[i] = grec[lo + i];
    hist[t] = 0u;
    __syncthreads();
    for (unsigned i = t; i < cnt; i += 256) atomicAdd(&hist[recs[i] >> 17], 1u);
    __syncthreads();
    unsigned v = hist[t];
    scan[t] = v;
    __syncthreads();
    for (int off = 1; off < 256; off <<= 1) {
        unsigned x = (t >= off) ? scan[t - off] : 0u;
        __syncthreads();
        scan[t] += x;
        __syncthreads();
    }
    unsigned excl = scan[t] - v;
    {
        int n = (s << SBSH) + t;
        if (n <= N_NODES) row_ptr[n] = lo + excl;
    }
    cur[t] = excl;
    __syncthreads();
    for (unsigned i = t; i < cnt; i += 256) {
        unsigned rec = recs[i];
        unsigned pos = atomicAdd(&cur[rec >> 17], 1u);
        grec[lo + pos] = rec & 0x1FFFFu;
    }
}

// pure CSR gather: 5 lanes per node, one float4 each; zero atomics.
__global__ __launch_bounds__(320) void k_gather(const unsigned* __restrict__ row_ptr,
                                                const unsigned* __restrict__ grec,
                                                const float* __restrict__ src,
                                                float* __restrict__ dst) {
    int gid = blockIdx.x * 320 + threadIdx.x;
    int node = gid / 5, q = gid % 5;
    if (node >= N_NODES) return;
    unsigned lo = row_ptr[node], hi = row_ptr[node + 1];
    float4 a0 = make_float4(0.f, 0.f, 0.f, 0.f);
    float4 a1 = make_float4(0.f, 0.f, 0.f, 0.f);
    float4 a2 = make_float4(0.f, 0.f, 0.f, 0.f);
    float4 a3 = make_float4(0.f, 0.f, 0.f, 0.f);
    unsigned e = lo;
    for (; e + 4 <= hi; e += 4) {
        unsigned s0 = grec[e], s1 = grec[e + 1], s2 = grec[e + 2], s3 = grec[e + 3];
        float4 v0 = ((const float4*)src)[s0 * 5 + q];
        float4 v1 = ((const float4*)src)[s1 * 5 + q];
        float4 v2 = ((const float4*)src)[s2 * 5 + q];
        float4 v3 = ((const float4*)src)[s3 * 5 + q];
        a0.x += v0.x; a0.y += v0.y; a0.z += v0.z; a0.w += v0.w;
        a1.x += v1.x; a1.y += v1.y; a1.z += v1.z; a1.w += v1.w;
        a2.x += v2.x; a2.y += v2.y; a2.z += v2.z; a2.w += v2.w;
        a3.x += v3.x; a3.y += v3.y; a3.z += v3.z; a3.w += v3.w;
    }
    for (; e < hi; ++e) {
        unsigned s0 = grec[e];
        float4 v0 = ((const float4*)src)[s0 * 5 + q];
        a0.x += v0.x; a0.y += v0.y; a0.z += v0.z; a0.w += v0.w;
    }
    a0.x += a1.x + a2.x + a3.x;
    a0.y += a1.y + a2.y + a3.y;
    a0.z += a1.z + a2.z + a3.z;
    a0.w += a1.w + a2.w + a3.w;
    float sc = rsqrtf(fmaxf((float)(hi - lo), 1.0f));
    a0.x *= sc; a0.y *= sc; a0.z *= sc; a0.w *= sc;
    ((float4*)dst)[node * 5 + q] = a0;
}

// FUSED gather1 + gc2: block = 64 nodes x 5 lanes (320 thr). Gather
// partials land in LDS h1[64][21]; barrier; thread-per-node applies
// the 20x20 GEMM (W2 LDS-broadcast) + relu/softmax + rs_s and writes
// h2_pre. Deletes the k_gc2 dispatch and 16 MB of agg round-trip.
__global__ __launch_bounds__(320) void k_gg1(const unsigned* __restrict__ row_ptr,
                                             const unsigned* __restrict__ grec,
                                             const float* __restrict__ src,
                                             const float* __restrict__ W2,
                                             const float* __restrict__ b2,
                                             const float* __restrict__ rs_s,
                                             float* __restrict__ h2_pre) {
    __shared__ float h1[64 * 21];          // 5,376 B
    __shared__ float Wsh[GC_HID * GC_HID];
    __shared__ float bsh[GC_HID];
    int t = threadIdx.x;
    if (t < GC_HID * GC_HID) Wsh[t] = W2[t];
    if (t >= 400 && t < 400 + GC_HID) bsh[t - 400] = b2[t - 400];
    int nl = t / 5, q = t % 5;
    int node = blockIdx.x * 64 + nl;
    bool live = (node < N_NODES);
    unsigned lo = 0, hi = 0;
    if (live) { lo = row_ptr[node]; hi = row_ptr[node + 1]; }
    float4 a0 = make_float4(0.f, 0.f, 0.f, 0.f);
    float4 a1 = make_float4(0.f, 0.f, 0.f, 0.f);
    float4 a2 = make_float4(0.f, 0.f, 0.f, 0.f);
    float4 a3 = make_float4(0.f, 0.f, 0.f, 0.f);
    unsigned e = lo;
    for (; e + 4 <= hi; e += 4) {
        unsigned s0 = grec[e], s1 = grec[e + 1], s2 = grec[e + 2], s3 = grec[e + 3];
        float4 v0 = ((const float4*)src)[s0 * 5 + q];
        float4 v1 = ((const float4*)src)[s1 * 5 + q];
        float4 v2 = ((const float4*)src)[s2 * 5 + q];
        float4 v3 = ((const float4*)src)[s3 * 5 + q];
        a0.x += v0.x; a0.y += v0.y; a0.z += v0.z; a0.w += v0.w;
        a1.x += v1.x; a1.y += v1.y; a1.z += v1.z; a1.w += v1.w;
        a2.x += v2.x; a2.y += v2.y; a2.z += v2.z; a2.w += v2.w;
        a3.x += v3.x; a3.y += v3.y; a3.z += v3.z; a3.w += v3.w;
    }
    for (; e < hi; ++e) {
        unsigned s0 = grec[e];
        float4 v0 = ((const float4*)src)[s0 * 5 + q];
        a0.x += v0.x; a0.y += v0.y; a0.z += v0.z; a0.w += v0.w;
    }
    a0.x += a1.x + a2.x + a3.x;
    a0.y += a1.y + a2.y + a3.y;
    a0.z += a1.z + a2.z + a3.z;
    a0.w += a1.w + a2.w + a3.w;
    if (live) {
        float sc = rsqrtf(fmaxf((float)(hi - lo), 1.0f));
        float* row = &h1[nl * 21 + q * 4];
        row[0] = a0.x * sc; row[1] = a0.y * sc;
        row[2] = a0.z * sc; row[3] = a0.w * sc;
    }
    __syncthreads();
    if (t < 64) {
        int nn = blockIdx.x * 64 + t;
        if (nn < N_NODES) {
            float hv[GC_HID];
#pragma unroll
            for (int i = 0; i < GC_HID; ++i) hv[i] = h1[t * 21 + i];
            float o[GC_HID];
#pragma unroll
            for (int j = 0; j < GC_HID; ++j) o[j] = bsh[j];
#pragma unroll
            for (int i = 0; i < GC_HID; ++i) {
                float x = hv[i];
#pragma unroll
                for (int j = 0; j < GC_HID; ++j) o[j] = fmaf(x, Wsh[i * GC_HID + j], o[j]);
            }
            float mx = -1e30f;
#pragma unroll
            for (int j = 0; j < GC_HID; ++j) { o[j] = fmaxf(o[j], 0.0f); mx = fmaxf(mx, o[j]); }
            float s = 0.0f;
#pragma unroll
            for (int j = 0; j < GC_HID; ++j) { o[j] = __expf(o[j] - mx); s += o[j]; }
            float inv = rs_s[nn] / s;
#pragma unroll
            for (int j = 0; j < GC_HID; ++j) o[j] *= inv;
            float4* op = (float4*)&h2_pre[(size_t)nn * GC_HID];
            op[0] = make_float4(o[0],  o[1],  o[2],  o[3]);
            op[1] = make_float4(o[4],  o[5],  o[6],  o[7]);
            op[2] = make_float4(o[8],  o[9],  o[10], o[11]);
            op[3] = make_float4(o[12], o[13], o[14], o[15]);
            op[4] = make_float4(o[16], o[17], o[18], o[19]);
        }
    }
}

// FUSED gc1 + encoder-partials (R21 local optimum): 256 thr (4 waves =
// 4 output groups), 64 nodes/block, 1563 blocks. Packed weights
// (K$-resident 384B row per k, s_load broadcast), double-buffered x-tile.
__global__ __launch_bounds__(256) void k_gc1f(const float* __restrict__ nodes,
                                              const float* __restrict__ Wp,
                                              const float* __restrict__ b1,
                                              const float* __restrict__ rs_s,
                                              float* __restrict__ h_pre,
                                              unsigned short* __restrict__ pml) {
    __shared__ float tile[2][64 * 33];     // 16,896 B
    float* gb = &tile[0][0];               // aliased after last buf0 use
    int t = threadIdx.x;
    int g = __builtin_amdgcn_readfirstlane(t >> 6);  // 0..3: packed-col group
    int lane = t & 63;
    int n0 = blockIdx.x * 64;
    int node = n0 + lane;

    {
        int idx = t;
#pragma unroll
        for (int r = 0; r < 2; ++r, idx += 256) {
            int rr = idx >> 3, c4 = idx & 7;
            int gn = n0 + rr;
            float4 v = (gn < N_NODES)
                ? ((const float4*)nodes)[(size_t)gn * 64 + c4]
                : make_float4(0.f, 0.f, 0.f, 0.f);
            float* dst = &tile[0][rr * 33 + c4 * 4];
            dst[0] = v.x; dst[1] = v.y; dst[2] = v.z; dst[3] = v.w;
        }
    }
    __syncthreads();

    float acc[24];
#pragma unroll
    for (int j = 0; j < 24; ++j) acc[j] = 0.0f;

    for (int c = 0; c < 8; ++c) {
        float4 p0, p1;
        if (c < 7) {
            int idx = t, rr = idx >> 3, c4 = idx & 7, gn = n0 + rr;
            p0 = (gn < N_NODES)
                ? ((const float4*)nodes)[(size_t)gn * 64 + (c + 1) * 8 + c4]
                : make_float4(0.f, 0.f, 0.f, 0.f);
            idx = t + 256; rr = idx >> 3; c4 = idx & 7; gn = n0 + rr;
            p1 = (gn < N_NODES)
                ? ((const float4*)nodes)[(size_t)gn * 64 + (c + 1) * 8 + c4]
                : make_float4(0.f, 0.f, 0.f, 0.f);
        }
        const float* trow  = &tile[c & 1][lane * 33];
        const float* wbase = Wp + (size_t)(c * 32) * 96 + g * 24;
#pragma unroll 4
        for (int kk = 0; kk < 32; ++kk) {
            float x = trow[kk];
            const float* wr = wbase + kk * 96;
#pragma unroll
            for (int j = 0; j < 24; ++j) acc[j] = fmaf(x, wr[j], acc[j]);
        }
        if (c < 7) {
            int idx = t, rr = idx >> 3, c4 = idx & 7;
            float* dst = &tile[(c + 1) & 1][rr * 33 + c4 * 4];
            dst[0] = p0.x; dst[1] = p0.y; dst[2] = p0.z; dst[3] = p0.w;
            idx = t + 256; rr = idx >> 3; c4 = idx & 7;
            dst = &tile[(c + 1) & 1][rr * 33 + c4 * 4];
            dst[0] = p1.x; dst[1] = p1.y; dst[2] = p1.z; dst[3] = p1.w;
        }
        __syncthreads();
    }

    if (node < N_NODES) {
        if (g == 0) {
#pragma unroll
            for (int j = 0; j < GC_HID; ++j) gb[lane * 21 + j] = acc[j] + b1[j];
        } else {
            int base = (g - 1) * 24;
            unsigned short* pp = pml + (size_t)node * 64 + base;
            uint4 q0, q1, q2;
            q0.x = (unsigned)f2bf(acc[0]) | ((unsigned)f2bf(acc[1]) << 16);
            q0.y = (unsigned)f2bf(acc[2]) | ((unsigned)f2bf(acc[3]) << 16);
            q0.z = (unsigned)f2bf(acc[4]) | ((unsigned)f2bf(acc[5]) << 16);
            q0.w = (unsigned)f2bf(acc[6]) | ((unsigned)f2bf(acc[7]) << 16);
            q1.x = (unsigned)f2bf(acc[8]) | ((unsigned)f2bf(acc[9]) << 16);
            q1.y = (unsigned)f2bf(acc[10]) | ((unsigned)f2bf(acc[11]) << 16);
            q1.z = (unsigned)f2bf(acc[12]) | ((unsigned)f2bf(acc[13]) << 16);
            q1.w = (unsigned)f2bf(acc[14]) | ((unsigned)f2bf(acc[15]) << 16);
            q2.x = (unsigned)f2bf(acc[16]) | ((unsigned)f2bf(acc[17]) << 16);
            q2.y = (unsigned)f2bf(acc[18]) | ((unsigned)f2bf(acc[19]) << 16);
            q2.z = (unsigned)f2bf(acc[20]) | ((unsigned)f2bf(acc[21]) << 16);
            q2.w = (unsigned)f2bf(acc[22]) | ((unsigned)f2bf(acc[23]) << 16);
            ((uint4*)pp)[0] = q0;
            ((uint4*)pp)[1] = q1;
            if (g != 3) ((uint4*)pp)[2] = q2;
        }
    }
    __syncthreads();
    if (t < 64) {
        int nn = n0 + t;
        if (nn < N_NODES) {
            float v[GC_HID];
            float mx = -1e30f;
#pragma unroll
            for (int j = 0; j < GC_HID; ++j) {
                v[j] = fmaxf(gb[t * 21 + j], 0.0f);
                mx = fmaxf(mx, v[j]);
            }
            float s = 0.0f;
#pragma unroll
            for (int j = 0; j < GC_HID; ++j) {
                v[j] = __expf(v[j] - mx);
                s += v[j];
            }
            float inv = rs_s[nn] / s;
#pragma unroll
            for (int j = 0; j < GC_HID; ++j) v[j] *= inv;
            float4* o = (float4*)&h_pre[(size_t)nn * GC_HID];
            o[0] = make_float4(v[0],  v[1],  v[2],  v[3]);
            o[1] = make_float4(v[4],  v[5],  v[6],  v[7]);
            o[2] = make_float4(v[8],  v[9],  v[10], v[11]);
            o[3] = make_float4(v[12], v[13], v[14], v[15]);
            o[4] = make_float4(v[16], v[17], v[18], v[19]);
        }
    }
}

// encoder finish: mu/ls = bias + pml + h2 @ W[0:20]. Octet split,
// grid (1563, 2), block 256 = 4 waves x 64 nodes.
__global__ __launch_bounds__(256) void k_enc2(const float* __restrict__ h2in,
                                              const unsigned short* __restrict__ pml,
                                              const float* __restrict__ Wmu,
                                              const float* __restrict__ bmu,
                                              const float* __restrict__ Wls,
                                              const float* __restrict__ bls,
                                              float* __restrict__ mu_out,
                                              float* __restrict__ ls_out) {
    int t = threadIdx.x;
    int wave = t >> 6, lane = t & 63;
    int og = __builtin_amdgcn_readfirstlane(wave | ((int)blockIdx.y << 2)); // 0..7
    int half = og >> 2;
    int co = (og & 3) << 3;
    int node = blockIdx.x * 64 + lane;
    if (node >= N_NODES) return;
    const float* W  = half ? Wls : Wmu;
    const float* bb = half ? bls : bmu;
    float* out      = half ? ls_out : mu_out;

    uint4 p = *(const uint4*)(pml + (size_t)node * 64 + half * 32 + co);
    float acc[8];
    acc[0] = bf2f((unsigned short)(p.x & 0xFFFFu));
    acc[1] = bf2f((unsigned short)(p.x >> 16));
    acc[2] = bf2f((unsigned short)(p.y & 0xFFFFu));
    acc[3] = bf2f((unsigned short)(p.y >> 16));
    acc[4] = bf2f((unsigned short)(p.z & 0xFFFFu));
    acc[5] = bf2f((unsigned short)(p.z >> 16));
    acc[6] = bf2f((unsigned short)(p.w & 0xFFFFu));
    acc[7] = bf2f((unsigned short)(p.w >> 16));
#pragma unroll
    for (int j = 0; j < 8; ++j) acc[j] += bb[co + j];

    const float4* hp = (const float4*)(h2in + (size_t)node * GC_HID);
#pragma unroll
    for (int v = 0; v < 5; ++v) {
        float4 hh = hp[v];
#pragma unroll
        for (int c = 0; c < 4; ++c) {
            float x = (c == 0) ? hh.x : (c == 1) ? hh.y : (c == 2) ? hh.z : hh.w;
            const float* wr = W + (v * 4 + c) * Z_DIM + co;
#pragma unroll
            for (int j = 0; j < 8; ++j) acc[j] = fmaf(x, wr[j], acc[j]);
        }
    }
    float4* op = (float4*)(out + (size_t)node * Z_DIM + co);
    op[0] = make_float4(acc[0], acc[1], acc[2], acc[3]);
    op[1] = make_float4(acc[4], acc[5], acc[6], acc[7]);
}

// decoder stage 1 (k_z fused): z computed in registers; d = relu(z@Wd1+bd1)
__global__ __launch_bounds__(256) void k_decd(const float* __restrict__ mu,
                                              const float* __restrict__ ls,
                                              const float* __restrict__ eps,
                                              const float* __restrict__ Wd1,
                                              const float* __restrict__ bd1,
                                              float* __restrict__ dbuf) {
    int node = blockIdx.x * 256 + threadIdx.x;
    if (node >= N_NODES) return;
    float d[DEC_HID];
#pragma unroll
    for (int j = 0; j < DEC_HID; ++j) d[j] = bd1[j];
    const float4* mp = (const float4*)(mu + (size_t)node * Z_DIM);
    const float4* lp = (const float4*)(ls + (size_t)node * Z_DIM);
    const float4* ep = (const float4*)(eps + (size_t)node * Z_DIM);
#pragma unroll
    for (int v = 0; v < Z_DIM / 4; ++v) {
        float4 m = mp[v], l = lp[v], e = ep[v];
        float4 zz;
        zz.x = m.x + (1e-4f + __expf(0.5f * l.x)) * e.x;
        zz.y = m.y + (1e-4f + __expf(0.5f * l.y)) * e.y;
        zz.z = m.z + (1e-4f + __expf(0.5f * l.z)) * e.z;
        zz.w = m.w + (1e-4f + __expf(0.5f * l.w)) * e.w;
#pragma unroll
        for (int c = 0; c < 4; ++c) {
            float x = (c == 0) ? zz.x : (c == 1) ? zz.y : (c == 2) ? zz.z : zz.w;
            const float* wr = Wd1 + (v * 4 + c) * DEC_HID;
#pragma unroll
            for (int j = 0; j < DEC_HID; ++j) d[j] = fmaf(x, wr[j], d[j]);
        }
    }
    float4* op = (float4*)(dbuf + (size_t)node * DEC_HID);
#pragma unroll
    for (int v = 0; v < DEC_HID / 4; ++v)
        op[v] = make_float4(fmaxf(d[4*v], 0.f), fmaxf(d[4*v+1], 0.f),
                            fmaxf(d[4*v+2], 0.f), fmaxf(d[4*v+3], 0.f));
}

// decoder stage 2: chunk id forced wave-uniform via readfirstlane; lane = node.
__global__ __launch_bounds__(256) void k_decx(const float* __restrict__ dbuf,
                                              const float* __restrict__ Wd2,
                                              const float* __restrict__ bd2,
                                              float* __restrict__ X) {
    int lane = threadIdx.x & 63;
    int wv   = threadIdx.x >> 6;             // 0..3
    int ch   = __builtin_amdgcn_readfirstlane(((blockIdx.x & 1) << 2) | wv);
    int node = (blockIdx.x >> 1) * 64 + lane;
    if (node >= N_NODES) return;
    int co = ch << 5;
    float o[32];
#pragma unroll
    for (int j = 0; j < 32; ++j) o[j] = bd2[co + j];
    const float4* dp = (const float4*)(dbuf + (size_t)node * DEC_HID);
#pragma unroll
    for (int v = 0; v < DEC_HID / 4; ++v) {
        float4 dd = dp[v];
#pragma unroll
        for (int c = 0; c < 4; ++c) {
            float x = (c == 0) ? dd.x : (c == 1) ? dd.y : (c == 2) ? dd.z : dd.w;
            const float* wr = Wd2 + (v * 4 + c) * D_FEAT + co;
#pragma unroll
            for (int j = 0; j < 32; ++j) o[j] = fmaf(x, wr[j], o[j]);
        }
    }
    float4* xp = (float4*)(X + (size_t)node * D_FEAT + co);
#pragma unroll
    for (int v = 0; v < 8; ++v)
        xp[v] = make_float4(o[4*v], o[4*v+1], o[4*v+2], o[4*v+3]);
}

extern "C" void kernel_launch(void* const* d_in, const int* in_sizes, int n_in,
                              void* d_out, int out_size, void* d_ws, size_t ws_size,
                              hipStream_t stream) {
    const float* nodes = (const float*)d_in[0];
    const int*   snd   = (const int*)d_in[1];
    const int*   rcv   = (const int*)d_in[2];
    const float* eps   = (const float*)d_in[3];
    const float* W1    = (const float*)d_in[4];
    const float* b1    = (const float*)d_in[5];
    const float* W2    = (const float*)d_in[6];
    const float* b2    = (const float*)d_in[7];
    const float* Wmu   = (const float*)d_in[8];
    const float* bmu   = (const float*)d_in[9];
    const float* Wls   = (const float*)d_in[10];
    const float* bls   = (const float*)d_in[11];
    const float* Wd1   = (const float*)d_in[12];
    const float* bd1   = (const float*)d_in[13];
    const float* Wd2   = (const float*)d_in[14];
    const float* bd2   = (const float*)d_in[15];

    char* ws = (char*)d_ws;
    float*          h_pre    = (float*)(ws);
    float*          agg      = (float*)(ws + 8000000);
    float*          dbuf     = (float*)(ws);              // overlays h_pre+agg (dead)
    unsigned*       grec     = (unsigned*)(ws + 16000000);
    unsigned*       rec_r    = (unsigned*)(ws + 28804096);
    unsigned short* pml      = (unsigned short*)(ws + 28804096); // overlays rec_r post-gscat
    unsigned short* srow_r   = (unsigned short*)(ws + 41608192);
    unsigned*       pref_t   = (unsigned*)(ws + 42836720);
    unsigned*       row_ptr  = (unsigned*)(ws + 45287504);
    unsigned*       gtot     = (unsigned*)(ws + 45687508);
    unsigned*       gbase    = (unsigned*)(ws + 45689076);
    float*          rs_s     = (float*)(ws + 45690648);
    unsigned char*  rec_s    = (unsigned char*)(ws + 46090648);
    unsigned short* srow_s   = (unsigned short*)(ws + 49291672);
    float*          Wpack    = (float*)(ws + 50520192);

    float* X      = (float*)d_out;
    float* mu_out = X + (size_t)N_NODES * D_FEAT;
    float* ls_out = mu_out + (size_t)N_NODES * Z_DIM;

    k_wpack<<<256, 96, 0, stream>>>(W1, Wmu, Wls, Wpack);
    k_sort<<<NBLK, 512, 0, stream>>>(snd, rcv, rec_r, rec_s, srow_r, srow_s);
    k_degs<<<SB, 512, 0, stream>>>(rec_s, srow_s, rs_s);
    k_scanB<<<SB, 256, 0, stream>>>(srow_r, pref_t, gtot);
    k_scanG<<<1, 512, 0, stream>>>(gtot, gbase);
    k_gscat<<<NBLK, 256, 0, stream>>>(rec_r, srow_r, pref_t, gbase, grec);
    k_sort2<<<SB, 256, 0, stream>>>(grec, gbase, row_ptr);

    k_gc1f<<<1563, 256, 0, stream>>>(nodes, Wpack, b1, rs_s, h_pre, pml);
    // fused gather1 + gc2 -> h2_pre in agg
    k_gg1<<<1563, 320, 0, stream>>>(row_ptr, grec, h_pre, W2, b2, rs_s, agg);
    // gather2: h2 (rs_r-normalized) -> reuse h_pre buffer
    k_gather<<<1563, 320, 0, stream>>>(row_ptr, grec, agg, h_pre);

    k_enc2<<<dim3(1563, 2), 256, 0, stream>>>(h_pre, pml, Wmu, bmu, Wls, bls,
                                              mu_out, ls_out);
    k_decd<<<391, 256, 0, stream>>>(mu_out, ls_out, eps, Wd1, bd1, dbuf);
    k_decx<<<3126, 256, 0, stream>>>(dbuf, Wd2, bd2, X);
}

// Round 25
// 403.915 us; speedup vs baseline: 1.0997x; 1.0344x over previous
//
#include <hip/hip_runtime.h>
#include <math.h>

#define N_NODES 100000
#define N_EDGES 3200000
#define D_FEAT 256
#define GC_HID 20
#define DEC_HID 40
#define Z_DIM 32

#define EPB 2048          // edges per sort block
#define NBLK 1563         // ceil(3.2M / 2048)
#define SB 392            // node buckets of 256 (392*256 = 100352)
#define SBSH 8
#define S2CAP 12288       // per-bucket record cap

// ---------------- ws layout (bytes) ----------------
// h_pre  @ 0           8,000,000
// agg    @ 8,000,000   8,000,000
// grec   @16,000,000  12,804,096
// rec_r  @28,804,096  12,804,096   (pml bf16 [N][64] overlays post-gscat)
// srow_r @41,608,192   1,228,518
// pref_t @42,836,720   2,450,784
// row_ptr@45,287,504     400,004
// gtot   @45,687,508       1,568
// gbase  @45,689,076       1,572
// rs_s   @45,690,648     400,000
// rec_s  @46,090,648   3,201,024
// srow_s @49,291,672   1,228,518
// Wpack  @50,520,192      98,304   end = 50,618,496

__device__ inline unsigned short f2bf(float f) {
    unsigned u = __float_as_uint(f);
    return (unsigned short)((u + 0x7FFFu + ((u >> 16) & 1u)) >> 16);
}
__device__ inline float bf2f(unsigned short h) {
    return __uint_as_float((unsigned)h << 16);
}

// pack node-row weights: Wpack[k][0:20]=W1[k], [24:56]=Wmu[20+k], [56:88]=Wls[20+k]
__global__ __launch_bounds__(96) void k_wpack(const float* __restrict__ W1,
                                              const float* __restrict__ Wmu,
                                              const float* __restrict__ Wls,
                                              float* __restrict__ Wp) {
    int k = blockIdx.x, j = threadIdx.x;
    float v = 0.0f;
    if (j < 20) v = W1[k * GC_HID + j];
    else if (j >= 24 && j < 56) v = Wmu[(GC_HID + k) * Z_DIM + (j - 24)];
    else if (j >= 56 && j < 88) v = Wls[(GC_HID + k) * Z_DIM + (j - 56)];
    Wp[k * 96 + j] = v;
}

// dual block-local counting sort (receiver u32 + sender u8 streams).
// ZERO global atomics (R13: each device-scope atomic = memory-side write).
__global__ __launch_bounds__(512) void k_sort(const int* __restrict__ snd,
                                              const int* __restrict__ rcv,
                                              unsigned* __restrict__ rec_r,
                                              unsigned char* __restrict__ rec_s,
                                              unsigned short* __restrict__ srow_r,
                                              unsigned short* __restrict__ srow_s) {
    __shared__ int es[EPB], er[EPB];
    __shared__ unsigned scan[SB + 1];
    __shared__ unsigned cur[SB];
    __shared__ unsigned sorted[EPB];
    __shared__ unsigned char sorteds[EPB];
    int b = blockIdx.x, t = threadIdx.x;
    int base = b * EPB;
    int cnt = min(EPB, N_EDGES - base);
    for (int i = t; i < cnt; i += 512) { es[i] = snd[base + i]; er[i] = rcv[base + i]; }

    for (int i = t; i < SB + 1; i += 512) scan[i] = 0u;
    __syncthreads();
    for (int i = t; i < cnt; i += 512) atomicAdd(&scan[(er[i] >> SBSH) + 1], 1u);
    __syncthreads();
    for (int off = 1; off < SB + 1; off <<= 1) {
        unsigned v = (t >= off && t < SB + 1) ? scan[t - off] : 0u;
        __syncthreads();
        if (t < SB + 1) scan[t] += v;
        __syncthreads();
    }
    for (int i = t; i < SB + 1; i += 512) srow_r[(size_t)b * (SB + 1) + i] = (unsigned short)scan[i];
    if (t < SB) cur[t] = scan[t];
    __syncthreads();
    for (int i = t; i < cnt; i += 512) {
        int r = er[i];
        unsigned pos = atomicAdd(&cur[r >> SBSH], 1u);
        sorted[pos] = ((unsigned)(r & 255) << 17) | (unsigned)es[i];
    }
    __syncthreads();
    for (int i = t; i < cnt; i += 512) rec_r[(size_t)base + i] = sorted[i];
    __syncthreads();

    for (int i = t; i < SB + 1; i += 512) scan[i] = 0u;
    __syncthreads();
    for (int i = t; i < cnt; i += 512) atomicAdd(&scan[(es[i] >> SBSH) + 1], 1u);
    __syncthreads();
    for (int off = 1; off < SB + 1; off <<= 1) {
        unsigned v = (t >= off && t < SB + 1) ? scan[t - off] : 0u;
        __syncthreads();
        if (t < SB + 1) scan[t] += v;
        __syncthreads();
    }
    for (int i = t; i < SB + 1; i += 512) srow_s[(size_t)b * (SB + 1) + i] = (unsigned short)scan[i];
    if (t < SB) cur[t] = scan[t];
    __syncthreads();
    for (int i = t; i < cnt; i += 512) {
        int s = es[i];
        unsigned pos = atomicAdd(&cur[s >> SBSH], 1u);
        sorteds[pos] = (unsigned char)(s & 255);
    }
    __syncthreads();
    for (int i = t; i < cnt; i += 512) rec_s[(size_t)base + i] = sorteds[i];
}

// sender-degree via per-bucket LDS histogram over sender-sorted runs
__global__ __launch_bounds__(512) void k_degs(const unsigned char* __restrict__ rec_s,
                                              const unsigned short* __restrict__ srow_s,
                                              float* __restrict__ rs_s) {
    __shared__ unsigned h[256];
    int s = blockIdx.x, t = threadIdx.x;
    if (t < 256) h[t] = 0u;
    __syncthreads();
    for (int k = t; k < NBLK; k += 512) {
        const unsigned short* row = srow_s + (size_t)k * (SB + 1);
        unsigned st = row[s], en = row[s + 1];
        const unsigned char* rp = rec_s + (size_t)k * EPB;
        for (unsigned i = st; i < en; ++i) atomicAdd(&h[rp[i]], 1u);
    }
    __syncthreads();
    if (t < 256) {
        int n = (s << SBSH) + t;
        if (n < N_NODES) rs_s[n] = rsqrtf(fmaxf((float)h[t], 1.0f));
    }
}

// per-bucket prefix over block segments: pref_t[s][k], totals gtot[s]
__global__ __launch_bounds__(256) void k_scanB(const unsigned short* __restrict__ srow_r,
                                               unsigned* __restrict__ pref_t,
                                               unsigned* __restrict__ gtot) {
    __shared__ unsigned buf[256];
    int s = blockIdx.x, t = threadIdx.x;
    unsigned run = 0;
    for (int k0 = 0; k0 < NBLK; k0 += 256) {
        int k = k0 + t;
        unsigned v = 0;
        if (k < NBLK) {
            const unsigned short* row = srow_r + (size_t)k * (SB + 1);
            v = (unsigned)row[s + 1] - (unsigned)row[s];
        }
        buf[t] = v;
        __syncthreads();
        for (int off = 1; off < 256; off <<= 1) {
            unsigned x = (t >= off) ? buf[t - off] : 0u;
            __syncthreads();
            buf[t] += x;
            __syncthreads();
        }
        if (k < NBLK) pref_t[(size_t)s * NBLK + k] = run + (buf[t] - v);
        unsigned tot = buf[255];
        __syncthreads();
        run += tot;
    }
    if (t == 0) gtot[s] = run;
}

// exclusive scan of bucket totals -> gbase[SB+1]
__global__ __launch_bounds__(512) void k_scanG(const unsigned* __restrict__ gtot,
                                               unsigned* __restrict__ gbase) {
    __shared__ unsigned buf[SB];
    int t = threadIdx.x;
    if (t < SB) buf[t] = gtot[t];
    __syncthreads();
    for (int off = 1; off < SB; off <<= 1) {
        unsigned x = (t >= off && t < SB) ? buf[t - off] : 0u;
        __syncthreads();
        if (t < SB) buf[t] += x;
        __syncthreads();
    }
    if (t < SB) gbase[t + 1] = buf[t];
    if (t == 0) gbase[0] = 0u;
}

// scatter block-sorted records to global bucket-sorted order
__global__ __launch_bounds__(256) void k_gscat(const unsigned* __restrict__ rec_r,
                                               const unsigned short* __restrict__ srow_r,
                                               const unsigned* __restrict__ pref_t,
                                               const unsigned* __restrict__ gbase,
                                               unsigned* __restrict__ grec) {
    __shared__ unsigned recs[EPB];
    __shared__ unsigned short srow[SB + 1];
    int b = blockIdx.x, t = threadIdx.x;
    int base = b * EPB;
    int cnt = min(EPB, N_EDGES - base);
    for (int i = t; i < cnt; i += 256) recs[i] = rec_r[(size_t)base + i];
    for (int i = t; i < SB + 1; i += 256) srow[i] = srow_r[(size_t)b * (SB + 1) + i];
    __syncthreads();
    for (int s = t; s < SB; s += 256) {
        unsigned lo = srow[s], hi = srow[s + 1];
        if (lo == hi) continue;
        unsigned dst = gbase[s] + pref_t[(size_t)s * NBLK + b];
        for (unsigned i = lo; i < hi; ++i) grec[dst + (i - lo)] = recs[i];
    }
}

// within-bucket counting sort by local receiver (in-place) + CSR row_ptr
__global__ __launch_bounds__(256) void k_sort2(unsigned* __restrict__ grec,
                                               const unsigned* __restrict__ gbase,
                                               unsigned* __restrict__ row_ptr) {
    __shared__ unsigned recs[S2CAP];     // 48 KB
    __shared__ unsigned hist[256];
    __shared__ unsigned scan[256];
    __shared__ unsigned cur[256];
    int s = blockIdx.x, t = threadIdx.x;
    unsigned lo = gbase[s], hi = gbase[s + 1];
    unsigned cnt = min(hi - lo, (unsigned)S2CAP);
    for (unsigned i = t; i < cnt; i += 256) recs[i] = grec[lo + i];
    hist[t] = 0u;
    __syncthreads();
    for (unsigned i = t; i < cnt; i += 256) atomicAdd(&hist[recs[i] >> 17], 1u);
    __syncthreads();
    unsigned v = hist[t];
    scan[t] = v;
    __syncthreads();
    for (int off = 1; off < 256; off <<= 1) {
        unsigned x = (t >= off) ? scan[t - off] : 0u;
        __syncthreads();
        scan[t] += x;
        __syncthreads();
    }
    unsigned excl = scan[t] - v;
    {
        int n = (s << SBSH) + t;
        if (n <= N_NODES) row_ptr[n] = lo + excl;
    }
    cur[t] = excl;
    __syncthreads();
    for (unsigned i = t; i < cnt; i += 256) {
        unsigned rec = recs[i];
        unsigned pos = atomicAdd(&cur[rec >> 17], 1u);
        grec[lo + pos] = rec & 0x1FFFFu;
    }
}

// FUSED gather1 + gc2: block = 64 nodes x 5 lanes (320 thr).
__global__ __launch_bounds__(320) void k_gg1(const unsigned* __restrict__ row_ptr,
                                             const unsigned* __restrict__ grec,
                                             const float* __restrict__ src,
                                             const float* __restrict__ W2,
                                             const float* __restrict__ b2,
                                             const float* __restrict__ rs_s,
                                             float* __restrict__ h2_pre) {
    __shared__ float h1[64 * 21];          // 5,376 B
    __shared__ float Wsh[GC_HID * GC_HID];
    __shared__ float bsh[GC_HID];
    int t = threadIdx.x;
    if (t < GC_HID * GC_HID) Wsh[t] = W2[t];
    if (t >= 400 && t < 400 + GC_HID) bsh[t - 400] = b2[t - 400];
    int nl = t / 5, q = t % 5;
    int node = blockIdx.x * 64 + nl;
    bool live = (node < N_NODES);
    unsigned lo = 0, hi = 0;
    if (live) { lo = row_ptr[node]; hi = row_ptr[node + 1]; }
    float4 a0 = make_float4(0.f, 0.f, 0.f, 0.f);
    float4 a1 = make_float4(0.f, 0.f, 0.f, 0.f);
    float4 a2 = make_float4(0.f, 0.f, 0.f, 0.f);
    float4 a3 = make_float4(0.f, 0.f, 0.f, 0.f);
    unsigned e = lo;
    for (; e + 4 <= hi; e += 4) {
        unsigned s0 = grec[e], s1 = grec[e + 1], s2 = grec[e + 2], s3 = grec[e + 3];
        float4 v0 = ((const float4*)src)[s0 * 5 + q];
        float4 v1 = ((const float4*)src)[s1 * 5 + q];
        float4 v2 = ((const float4*)src)[s2 * 5 + q];
        float4 v3 = ((const float4*)src)[s3 * 5 + q];
        a0.x += v0.x; a0.y += v0.y; a0.z += v0.z; a0.w += v0.w;
        a1.x += v1.x; a1.y += v1.y; a1.z += v1.z; a1.w += v1.w;
        a2.x += v2.x; a2.y += v2.y; a2.z += v2.z; a2.w += v2.w;
        a3.x += v3.x; a3.y += v3.y; a3.z += v3.z; a3.w += v3.w;
    }
    for (; e < hi; ++e) {
        unsigned s0 = grec[e];
        float4 v0 = ((const float4*)src)[s0 * 5 + q];
        a0.x += v0.x; a0.y += v0.y; a0.z += v0.z; a0.w += v0.w;
    }
    a0.x += a1.x + a2.x + a3.x;
    a0.y += a1.y + a2.y + a3.y;
    a0.z += a1.z + a2.z + a3.z;
    a0.w += a1.w + a2.w + a3.w;
    if (live) {
        float sc = rsqrtf(fmaxf((float)(hi - lo), 1.0f));
        float* row = &h1[nl * 21 + q * 4];
        row[0] = a0.x * sc; row[1] = a0.y * sc;
        row[2] = a0.z * sc; row[3] = a0.w * sc;
    }
    __syncthreads();
    if (t < 64) {
        int nn = blockIdx.x * 64 + t;
        if (nn < N_NODES) {
            float hv[GC_HID];
#pragma unroll
            for (int i = 0; i < GC_HID; ++i) hv[i] = h1[t * 21 + i];
            float o[GC_HID];
#pragma unroll
            for (int j = 0; j < GC_HID; ++j) o[j] = bsh[j];
#pragma unroll
            for (int i = 0; i < GC_HID; ++i) {
                float x = hv[i];
#pragma unroll
                for (int j = 0; j < GC_HID; ++j) o[j] = fmaf(x, Wsh[i * GC_HID + j], o[j]);
            }
            float mx = -1e30f;
#pragma unroll
            for (int j = 0; j < GC_HID; ++j) { o[j] = fmaxf(o[j], 0.0f); mx = fmaxf(mx, o[j]); }
            float s = 0.0f;
#pragma unroll
            for (int j = 0; j < GC_HID; ++j) { o[j] = __expf(o[j] - mx); s += o[j]; }
            float inv = rs_s[nn] / s;
#pragma unroll
            for (int j = 0; j < GC_HID; ++j) o[j] *= inv;
            float4* op = (float4*)&h2_pre[(size_t)nn * GC_HID];
            op[0] = make_float4(o[0],  o[1],  o[2],  o[3]);
            op[1] = make_float4(o[4],  o[5],  o[6],  o[7]);
            op[2] = make_float4(o[8],  o[9],  o[10], o[11]);
            op[3] = make_float4(o[12], o[13], o[14], o[15]);
            op[4] = make_float4(o[16], o[17], o[18], o[19]);
        }
    }
}

// FUSED gather2 + encoder finish: 512 thr, 64 nodes. Waves 0-4 gather
// h2 into LDS [64][21]; barrier; all 8 waves run octet-split enc head
// (og = readfirstlane(wave), weights s_load). Deletes the 8 MB h_pre
// round-trip and a dispatch.
__global__ __launch_bounds__(512) void k_gg2(const unsigned* __restrict__ row_ptr,
                                             const unsigned* __restrict__ grec,
                                             const float* __restrict__ src,
                                             const unsigned short* __restrict__ pml,
                                             const float* __restrict__ Wmu,
                                             const float* __restrict__ bmu,
                                             const float* __restrict__ Wls,
                                             const float* __restrict__ bls,
                                             float* __restrict__ mu_out,
                                             float* __restrict__ ls_out) {
    __shared__ float h2s[64 * 21];         // 5,376 B
    int t = threadIdx.x;
    int n0 = blockIdx.x * 64;
    if (t < 320) {
        int nl = t / 5, q = t % 5;
        int node = n0 + nl;
        bool live = (node < N_NODES);
        unsigned lo = 0, hi = 0;
        if (live) { lo = row_ptr[node]; hi = row_ptr[node + 1]; }
        float4 a0 = make_float4(0.f, 0.f, 0.f, 0.f);
        float4 a1 = make_float4(0.f, 0.f, 0.f, 0.f);
        float4 a2 = make_float4(0.f, 0.f, 0.f, 0.f);
        float4 a3 = make_float4(0.f, 0.f, 0.f, 0.f);
        unsigned e = lo;
        for (; e + 4 <= hi; e += 4) {
            unsigned s0 = grec[e], s1 = grec[e + 1], s2 = grec[e + 2], s3 = grec[e + 3];
            float4 v0 = ((const float4*)src)[s0 * 5 + q];
            float4 v1 = ((const float4*)src)[s1 * 5 + q];
            float4 v2 = ((const float4*)src)[s2 * 5 + q];
            float4 v3 = ((const float4*)src)[s3 * 5 + q];
            a0.x += v0.x; a0.y += v0.y; a0.z += v0.z; a0.w += v0.w;
            a1.x += v1.x; a1.y += v1.y; a1.z += v1.z; a1.w += v1.w;
            a2.x += v2.x; a2.y += v2.y; a2.z += v2.z; a2.w += v2.w;
            a3.x += v3.x; a3.y += v3.y; a3.z += v3.z; a3.w += v3.w;
        }
        for (; e < hi; ++e) {
            unsigned s0 = grec[e];
            float4 v0 = ((const float4*)src)[s0 * 5 + q];
            a0.x += v0.x; a0.y += v0.y; a0.z += v0.z; a0.w += v0.w;
        }
        a0.x += a1.x + a2.x + a3.x;
        a0.y += a1.y + a2.y + a3.y;
        a0.z += a1.z + a2.z + a3.z;
        a0.w += a1.w + a2.w + a3.w;
        if (live) {
            float sc = rsqrtf(fmaxf((float)(hi - lo), 1.0f));
            float* row = &h2s[nl * 21 + q * 4];
            row[0] = a0.x * sc; row[1] = a0.y * sc;
            row[2] = a0.z * sc; row[3] = a0.w * sc;
        }
    }
    __syncthreads();
    // encoder head: og per wave (0..7)
    int wave = t >> 6, lane = t & 63;
    int og = __builtin_amdgcn_readfirstlane(wave);
    int half = og >> 2;
    int co = (og & 3) << 3;
    int node = n0 + lane;
    if (node >= N_NODES) return;
    const float* W  = half ? Wls : Wmu;
    const float* bb = half ? bls : bmu;
    float* out      = half ? ls_out : mu_out;

    uint4 p = *(const uint4*)(pml + (size_t)node * 64 + half * 32 + co);
    float acc[8];
    acc[0] = bf2f((unsigned short)(p.x & 0xFFFFu));
    acc[1] = bf2f((unsigned short)(p.x >> 16));
    acc[2] = bf2f((unsigned short)(p.y & 0xFFFFu));
    acc[3] = bf2f((unsigned short)(p.y >> 16));
    acc[4] = bf2f((unsigned short)(p.z & 0xFFFFu));
    acc[5] = bf2f((unsigned short)(p.z >> 16));
    acc[6] = bf2f((unsigned short)(p.w & 0xFFFFu));
    acc[7] = bf2f((unsigned short)(p.w >> 16));
#pragma unroll
    for (int j = 0; j < 8; ++j) acc[j] += bb[co + j];

#pragma unroll
    for (int i = 0; i < GC_HID; ++i) {
        float x = h2s[lane * 21 + i];
        const float* wr = W + i * Z_DIM + co;
#pragma unroll
        for (int j = 0; j < 8; ++j) acc[j] = fmaf(x, wr[j], acc[j]);
    }
    float4* op = (float4*)(out + (size_t)node * Z_DIM + co);
    op[0] = make_float4(acc[0], acc[1], acc[2], acc[3]);
    op[1] = make_float4(acc[4], acc[5], acc[6], acc[7]);
}

// FUSED gc1 + encoder-partials (R21 local optimum): 256 thr (4 waves =
// 4 output groups), 64 nodes/block, 1563 blocks. Packed weights
// (K$-resident 384B row per k, s_load broadcast), double-buffered x-tile.
__global__ __launch_bounds__(256) void k_gc1f(const float* __restrict__ nodes,
                                              const float* __restrict__ Wp,
                                              const float* __restrict__ b1,
                                              const float* __restrict__ rs_s,
                                              float* __restrict__ h_pre,
                                              unsigned short* __restrict__ pml) {
    __shared__ float tile[2][64 * 33];     // 16,896 B
    float* gb = &tile[0][0];               // aliased after last buf0 use
    int t = threadIdx.x;
    int g = __builtin_amdgcn_readfirstlane(t >> 6);  // 0..3: packed-col group
    int lane = t & 63;
    int n0 = blockIdx.x * 64;
    int node = n0 + lane;

    {
        int idx = t;
#pragma unroll
        for (int r = 0; r < 2; ++r, idx += 256) {
            int rr = idx >> 3, c4 = idx & 7;
            int gn = n0 + rr;
            float4 v = (gn < N_NODES)
                ? ((const float4*)nodes)[(size_t)gn * 64 + c4]
                : make_float4(0.f, 0.f, 0.f, 0.f);
            float* dst = &tile[0][rr * 33 + c4 * 4];
            dst[0] = v.x; dst[1] = v.y; dst[2] = v.z; dst[3] = v.w;
        }
    }
    __syncthreads();

    float acc[24];
#pragma unroll
    for (int j = 0; j < 24; ++j) acc[j] = 0.0f;

    for (int c = 0; c < 8; ++c) {
        float4 p0, p1;
        if (c < 7) {
            int idx = t, rr = idx >> 3, c4 = idx & 7, gn = n0 + rr;
            p0 = (gn < N_NODES)
                ? ((const float4*)nodes)[(size_t)gn * 64 + (c + 1) * 8 + c4]
                : make_float4(0.f, 0.f, 0.f, 0.f);
            idx = t + 256; rr = idx >> 3; c4 = idx & 7; gn = n0 + rr;
            p1 = (gn < N_NODES)
                ? ((const float4*)nodes)[(size_t)gn * 64 + (c + 1) * 8 + c4]
                : make_float4(0.f, 0.f, 0.f, 0.f);
        }
        const float* trow  = &tile[c & 1][lane * 33];
        const float* wbase = Wp + (size_t)(c * 32) * 96 + g * 24;
#pragma unroll 4
        for (int kk = 0; kk < 32; ++kk) {
            float x = trow[kk];
            const float* wr = wbase + kk * 96;
#pragma unroll
            for (int j = 0; j < 24; ++j) acc[j] = fmaf(x, wr[j], acc[j]);
        }
        if (c < 7) {
            int idx = t, rr = idx >> 3, c4 = idx & 7;
            float* dst = &tile[(c + 1) & 1][rr * 33 + c4 * 4];
            dst[0] = p0.x; dst[1] = p0.y; dst[2] = p0.z; dst[3] = p0.w;
            idx = t + 256; rr = idx >> 3; c4 = idx & 7;
            dst = &tile[(c + 1) & 1][rr * 33 + c4 * 4];
            dst[0] = p1.x; dst[1] = p1.y; dst[2] = p1.z; dst[3] = p1.w;
        }
        __syncthreads();
    }

    if (node < N_NODES) {
        if (g == 0) {
#pragma unroll
            for (int j = 0; j < GC_HID; ++j) gb[lane * 21 + j] = acc[j] + b1[j];
        } else {
            int base = (g - 1) * 24;
            unsigned short* pp = pml + (size_t)node * 64 + base;
            uint4 q0, q1, q2;
            q0.x = (unsigned)f2bf(acc[0]) | ((unsigned)f2bf(acc[1]) << 16);
            q0.y = (unsigned)f2bf(acc[2]) | ((unsigned)f2bf(acc[3]) << 16);
            q0.z = (unsigned)f2bf(acc[4]) | ((unsigned)f2bf(acc[5]) << 16);
            q0.w = (unsigned)f2bf(acc[6]) | ((unsigned)f2bf(acc[7]) << 16);
            q1.x = (unsigned)f2bf(acc[8]) | ((unsigned)f2bf(acc[9]) << 16);
            q1.y = (unsigned)f2bf(acc[10]) | ((unsigned)f2bf(acc[11]) << 16);
            q1.z = (unsigned)f2bf(acc[12]) | ((unsigned)f2bf(acc[13]) << 16);
            q1.w = (unsigned)f2bf(acc[14]) | ((unsigned)f2bf(acc[15]) << 16);
            q2.x = (unsigned)f2bf(acc[16]) | ((unsigned)f2bf(acc[17]) << 16);
            q2.y = (unsigned)f2bf(acc[18]) | ((unsigned)f2bf(acc[19]) << 16);
            q2.z = (unsigned)f2bf(acc[20]) | ((unsigned)f2bf(acc[21]) << 16);
            q2.w = (unsigned)f2bf(acc[22]) | ((unsigned)f2bf(acc[23]) << 16);
            ((uint4*)pp)[0] = q0;
            ((uint4*)pp)[1] = q1;
            if (g != 3) ((uint4*)pp)[2] = q2;
        }
    }
    __syncthreads();
    if (t < 64) {
        int nn = n0 + t;
        if (nn < N_NODES) {
            float v[GC_HID];
            float mx = -1e30f;
#pragma unroll
            for (int j = 0; j < GC_HID; ++j) {
                v[j] = fmaxf(gb[t * 21 + j], 0.0f);
                mx = fmaxf(mx, v[j]);
            }
            float s = 0.0f;
#pragma unroll
            for (int j = 0; j < GC_HID; ++j) {
                v[j] = __expf(v[j] - mx);
                s += v[j];
            }
            float inv = rs_s[nn] / s;
#pragma unroll
            for (int j = 0; j < GC_HID; ++j) v[j] *= inv;
            float4* o = (float4*)&h_pre[(size_t)nn * GC_HID];
            o[0] = make_float4(v[0],  v[1],  v[2],  v[3]);
            o[1] = make_float4(v[4],  v[5],  v[6],  v[7]);
            o[2] = make_float4(v[8],  v[9],  v[10], v[11]);
            o[3] = make_float4(v[12], v[13], v[14], v[15]);
            o[4] = make_float4(v[16], v[17], v[18], v[19]);
        }
    }
}

// FUSED decoder (decd + decx): 512 thr, 128 nodes/block, 782 blocks.
// Phase 1: wave-uniform quarter split (qd = wave&3, nh = wave>>2) --
// each thread computes z (4x redundant, cheap) and a 10-wide d-slice,
// parks in LDS [128][41] (41 odd -> conflict-free). Phase 2: 2 passes,
// ch = readfirstlane(wave>>1)+4p wave-uniform, 32 X-outputs/thread.
__global__ __launch_bounds__(512) void k_dec(const float* __restrict__ mu,
                                             const float* __restrict__ ls,
                                             const float* __restrict__ eps,
                                             const float* __restrict__ Wd1,
                                             const float* __restrict__ bd1,
                                             const float* __restrict__ Wd2,
                                             const float* __restrict__ bd2,
                                             float* __restrict__ X) {
    __shared__ float ds[128 * 41];         // 20,992 B
    int t = threadIdx.x;
    int wave = t >> 6, lane = t & 63;
    int n0 = blockIdx.x * 128;
    {
        int wu = __builtin_amdgcn_readfirstlane(wave);
        int qd = wu & 3;               // d-quarter: outputs qd*10 .. +9
        int nh = wu >> 2;              // node half
        int nrow = nh * 64 + lane;     // 0..127
        int node = n0 + nrow;
        if (node < N_NODES) {
            float z[Z_DIM];
            const float4* mp = (const float4*)(mu + (size_t)node * Z_DIM);
            const float4* lp = (const float4*)(ls + (size_t)node * Z_DIM);
            const float4* ep = (const float4*)(eps + (size_t)node * Z_DIM);
#pragma unroll
            for (int v = 0; v < Z_DIM / 4; ++v) {
                float4 m = mp[v], l = lp[v], e = ep[v];
                z[4*v+0] = m.x + (1e-4f + __expf(0.5f * l.x)) * e.x;
                z[4*v+1] = m.y + (1e-4f + __expf(0.5f * l.y)) * e.y;
                z[4*v+2] = m.z + (1e-4f + __expf(0.5f * l.z)) * e.z;
                z[4*v+3] = m.w + (1e-4f + __expf(0.5f * l.w)) * e.w;
            }
            float d[10];
#pragma unroll
            for (int j = 0; j < 10; ++j) d[j] = bd1[qd * 10 + j];
#pragma unroll
            for (int i = 0; i < Z_DIM; ++i) {
                float x = z[i];
                const float* wr = Wd1 + i * DEC_HID + qd * 10;
#pragma unroll
                for (int j = 0; j < 10; ++j) d[j] = fmaf(x, wr[j], d[j]);
            }
            float* dst = &ds[nrow * 41 + qd * 10];
#pragma unroll
            for (int j = 0; j < 10; ++j) dst[j] = fmaxf(d[j], 0.0f);
        }
    }
    __syncthreads();
#pragma unroll
    for (int p = 0; p < 2; ++p) {
        int ch = __builtin_amdgcn_readfirstlane(wave >> 1) + p * 4;  // 0..7
        int nrow = (wave & 1) * 64 + lane;     // 0..127
        int node = n0 + nrow;
        if (node < N_NODES) {
            int co = ch << 5;
            float o[32];
#pragma unroll
            for (int j = 0; j < 32; ++j) o[j] = bd2[co + j];
            const float* drow = &ds[nrow * 41];
#pragma unroll 8
            for (int k = 0; k < DEC_HID; ++k) {
                float x = drow[k];
                const float* wr = Wd2 + k * D_FEAT + co;
#pragma unroll
                for (int j = 0; j < 32; ++j) o[j] = fmaf(x, wr[j], o[j]);
            }
            float4* xp = (float4*)(X + (size_t)node * D_FEAT + co);
#pragma unroll
            for (int v = 0; v < 8; ++v)
                xp[v] = make_float4(o[4*v], o[4*v+1], o[4*v+2], o[4*v+3]);
        }
    }
}

extern "C" void kernel_launch(void* const* d_in, const int* in_sizes, int n_in,
                              void* d_out, int out_size, void* d_ws, size_t ws_size,
                              hipStream_t stream) {
    const float* nodes = (const float*)d_in[0];
    const int*   snd   = (const int*)d_in[1];
    const int*   rcv   = (const int*)d_in[2];
    const float* eps   = (const float*)d_in[3];
    const float* W1    = (const float*)d_in[4];
    const float* b1    = (const float*)d_in[5];
    const float* W2    = (const float*)d_in[6];
    const float* b2    = (const float*)d_in[7];
    const float* Wmu   = (const float*)d_in[8];
    const float* bmu   = (const float*)d_in[9];
    const float* Wls   = (const float*)d_in[10];
    const float* bls   = (const float*)d_in[11];
    const float* Wd1   = (const float*)d_in[12];
    const float* bd1   = (const float*)d_in[13];
    const float* Wd2   = (const float*)d_in[14];
    const float* bd2   = (const float*)d_in[15];

    char* ws = (char*)d_ws;
    float*          h_pre    = (float*)(ws);
    float*          agg      = (float*)(ws + 8000000);
    unsigned*       grec     = (unsigned*)(ws + 16000000);
    unsigned*       rec_r    = (unsigned*)(ws + 28804096);
    unsigned short* pml      = (unsigned short*)(ws + 28804096); // overlays rec_r post-gscat
    unsigned short* srow_r   = (unsigned short*)(ws + 41608192);
    unsigned*       pref_t   = (unsigned*)(ws + 42836720);
    unsigned*       row_ptr  = (unsigned*)(ws + 45287504);
    unsigned*       gtot     = (unsigned*)(ws + 45687508);
    unsigned*       gbase    = (unsigned*)(ws + 45689076);
    float*          rs_s     = (float*)(ws + 45690648);
    unsigned char*  rec_s    = (unsigned char*)(ws + 46090648);
    unsigned short* srow_s   = (unsigned short*)(ws + 49291672);
    float*          Wpack    = (float*)(ws + 50520192);

    float* X      = (float*)d_out;
    float* mu_out = X + (size_t)N_NODES * D_FEAT;
    float* ls_out = mu_out + (size_t)N_NODES * Z_DIM;

    k_wpack<<<256, 96, 0, stream>>>(W1, Wmu, Wls, Wpack);
    k_sort<<<NBLK, 512, 0, stream>>>(snd, rcv, rec_r, rec_s, srow_r, srow_s);
    k_degs<<<SB, 512, 0, stream>>>(rec_s, srow_s, rs_s);
    k_scanB<<<SB, 256, 0, stream>>>(srow_r, pref_t, gtot);
    k_scanG<<<1, 512, 0, stream>>>(gtot, gbase);
    k_gscat<<<NBLK, 256, 0, stream>>>(rec_r, srow_r, pref_t, gbase, grec);
    k_sort2<<<SB, 256, 0, stream>>>(grec, gbase, row_ptr);

    k_gc1f<<<1563, 256, 0, stream>>>(nodes, Wpack, b1, rs_s, h_pre, pml);
    // fused gather1 + gc2 -> h2_pre in agg
    k_gg1<<<1563, 320, 0, stream>>>(row_ptr, grec, h_pre, W2, b2, rs_s, agg);
    // fused gather2 + encoder head -> mu/ls
    k_gg2<<<1563, 512, 0, stream>>>(row_ptr, grec, agg, pml, Wmu, bmu, Wls, bls,
                                    mu_out, ls_out);
    // fused decoder (z + d + X)
    k_dec<<<782, 512, 0, stream>>>(mu_out, ls_out, eps, Wd1, bd1, Wd2, bd2, X);
}

// Round 26
// 358.465 us; speedup vs baseline: 1.2391x; 1.1268x over previous
//
#include <hip/hip_runtime.h>
#include <math.h>

#define N_NODES 100000
#define N_EDGES 3200000
#define D_FEAT 256
#define GC_HID 20
#define DEC_HID 40
#define Z_DIM 32

#define EPB 2048          // edges per sort block
#define NBLK 1563         // ceil(3.2M / 2048)
#define SB 392            // node buckets of 256 (392*256 = 100352)
#define SBSH 8
#define S2CAP 12288       // per-bucket record cap

// ---------------- ws layout (bytes) ----------------
// h_pre (bf16 [N][20]) @ 0          4,000,000
// agg   (bf16 [N][20]) @ 8,000,000  4,000,000
// grec   @16,000,000  12,804,096
// rec_r  @28,804,096  12,804,096   (pml bf16 [N][64] overlays post-gscat)
// srow_r @41,608,192   1,228,518
// pref_t @42,836,720   2,450,784
// row_ptr@45,287,504     400,004
// gtot   @45,687,508       1,568
// gbase  @45,689,076       1,572
// rs_s   @45,690,648     400,000
// rec_s  @46,090,648   3,201,024
// srow_s @49,291,672   1,228,518
// Wpack  @50,520,192      98,304   end = 50,618,496

__device__ inline unsigned short f2bf(float f) {
    unsigned u = __float_as_uint(f);
    return (unsigned short)((u + 0x7FFFu + ((u >> 16) & 1u)) >> 16);
}
__device__ inline float bf2f(unsigned short h) {
    return __uint_as_float((unsigned)h << 16);
}
__device__ inline float bflo(unsigned w) { return __uint_as_float(w << 16); }
__device__ inline float bfhi(unsigned w) { return __uint_as_float(w & 0xFFFF0000u); }

// pack node-row weights: Wpack[k][0:20]=W1[k], [24:56]=Wmu[20+k], [56:88]=Wls[20+k]
__global__ __launch_bounds__(96) void k_wpack(const float* __restrict__ W1,
                                              const float* __restrict__ Wmu,
                                              const float* __restrict__ Wls,
                                              float* __restrict__ Wp) {
    int k = blockIdx.x, j = threadIdx.x;
    float v = 0.0f;
    if (j < 20) v = W1[k * GC_HID + j];
    else if (j >= 24 && j < 56) v = Wmu[(GC_HID + k) * Z_DIM + (j - 24)];
    else if (j >= 56 && j < 88) v = Wls[(GC_HID + k) * Z_DIM + (j - 56)];
    Wp[k * 96 + j] = v;
}

// dual block-local counting sort (receiver u32 + sender u8 streams).
// ZERO global atomics (R13: each device-scope atomic = memory-side write).
__global__ __launch_bounds__(512) void k_sort(const int* __restrict__ snd,
                                              const int* __restrict__ rcv,
                                              unsigned* __restrict__ rec_r,
                                              unsigned char* __restrict__ rec_s,
                                              unsigned short* __restrict__ srow_r,
                                              unsigned short* __restrict__ srow_s) {
    __shared__ int es[EPB], er[EPB];
    __shared__ unsigned scan[SB + 1];
    __shared__ unsigned cur[SB];
    __shared__ unsigned sorted[EPB];
    __shared__ unsigned char sorteds[EPB];
    int b = blockIdx.x, t = threadIdx.x;
    int base = b * EPB;
    int cnt = min(EPB, N_EDGES - base);
    for (int i = t; i < cnt; i += 512) { es[i] = snd[base + i]; er[i] = rcv[base + i]; }

    for (int i = t; i < SB + 1; i += 512) scan[i] = 0u;
    __syncthreads();
    for (int i = t; i < cnt; i += 512) atomicAdd(&scan[(er[i] >> SBSH) + 1], 1u);
    __syncthreads();
    for (int off = 1; off < SB + 1; off <<= 1) {
        unsigned v = (t >= off && t < SB + 1) ? scan[t - off] : 0u;
        __syncthreads();
        if (t < SB + 1) scan[t] += v;
        __syncthreads();
    }
    for (int i = t; i < SB + 1; i += 512) srow_r[(size_t)b * (SB + 1) + i] = (unsigned short)scan[i];
    if (t < SB) cur[t] = scan[t];
    __syncthreads();
    for (int i = t; i < cnt; i += 512) {
        int r = er[i];
        unsigned pos = atomicAdd(&cur[r >> SBSH], 1u);
        sorted[pos] = ((unsigned)(r & 255) << 17) | (unsigned)es[i];
    }
    __syncthreads();
    for (int i = t; i < cnt; i += 512) rec_r[(size_t)base + i] = sorted[i];
    __syncthreads();

    for (int i = t; i < SB + 1; i += 512) scan[i] = 0u;
    __syncthreads();
    for (int i = t; i < cnt; i += 512) atomicAdd(&scan[(es[i] >> SBSH) + 1], 1u);
    __syncthreads();
    for (int off = 1; off < SB + 1; off <<= 1) {
        unsigned v = (t >= off && t < SB + 1) ? scan[t - off] : 0u;
        __syncthreads();
        if (t < SB + 1) scan[t] += v;
        __syncthreads();
    }
    for (int i = t; i < SB + 1; i += 512) srow_s[(size_t)b * (SB + 1) + i] = (unsigned short)scan[i];
    if (t < SB) cur[t] = scan[t];
    __syncthreads();
    for (int i = t; i < cnt; i += 512) {
        int s = es[i];
        unsigned pos = atomicAdd(&cur[s >> SBSH], 1u);
        sorteds[pos] = (unsigned char)(s & 255);
    }
    __syncthreads();
    for (int i = t; i < cnt; i += 512) rec_s[(size_t)base + i] = sorteds[i];
}

// sender-degree via per-bucket LDS histogram over sender-sorted runs
__global__ __launch_bounds__(512) void k_degs(const unsigned char* __restrict__ rec_s,
                                              const unsigned short* __restrict__ srow_s,
                                              float* __restrict__ rs_s) {
    __shared__ unsigned h[256];
    int s = blockIdx.x, t = threadIdx.x;
    if (t < 256) h[t] = 0u;
    __syncthreads();
    for (int k = t; k < NBLK; k += 512) {
        const unsigned short* row = srow_s + (size_t)k * (SB + 1);
        unsigned st = row[s], en = row[s + 1];
        const unsigned char* rp = rec_s + (size_t)k * EPB;
        for (unsigned i = st; i < en; ++i) atomicAdd(&h[rp[i]], 1u);
    }
    __syncthreads();
    if (t < 256) {
        int n = (s << SBSH) + t;
        if (n < N_NODES) rs_s[n] = rsqrtf(fmaxf((float)h[t], 1.0f));
    }
}

// per-bucket prefix over block segments: pref_t[s][k], totals gtot[s]
__global__ __launch_bounds__(256) void k_scanB(const unsigned short* __restrict__ srow_r,
                                               unsigned* __restrict__ pref_t,
                                               unsigned* __restrict__ gtot) {
    __shared__ unsigned buf[256];
    int s = blockIdx.x, t = threadIdx.x;
    unsigned run = 0;
    for (int k0 = 0; k0 < NBLK; k0 += 256) {
        int k = k0 + t;
        unsigned v = 0;
        if (k < NBLK) {
            const unsigned short* row = srow_r + (size_t)k * (SB + 1);
            v = (unsigned)row[s + 1] - (unsigned)row[s];
        }
        buf[t] = v;
        __syncthreads();
        for (int off = 1; off < 256; off <<= 1) {
            unsigned x = (t >= off) ? buf[t - off] : 0u;
            __syncthreads();
            buf[t] += x;
            __syncthreads();
        }
        if (k < NBLK) pref_t[(size_t)s * NBLK + k] = run + (buf[t] - v);
        unsigned tot = buf[255];
        __syncthreads();
        run += tot;
    }
    if (t == 0) gtot[s] = run;
}

// exclusive scan of bucket totals -> gbase[SB+1]
__global__ __launch_bounds__(512) void k_scanG(const unsigned* __restrict__ gtot,
                                               unsigned* __restrict__ gbase) {
    __shared__ unsigned buf[SB];
    int t = threadIdx.x;
    if (t < SB) buf[t] = gtot[t];
    __syncthreads();
    for (int off = 1; off < SB; off <<= 1) {
        unsigned x = (t >= off && t < SB) ? buf[t - off] : 0u;
        __syncthreads();
        if (t < SB) buf[t] += x;
        __syncthreads();
    }
    if (t < SB) gbase[t + 1] = buf[t];
    if (t == 0) gbase[0] = 0u;
}

// scatter block-sorted records to global bucket-sorted order
__global__ __launch_bounds__(256) void k_gscat(const unsigned* __restrict__ rec_r,
                                               const unsigned short* __restrict__ srow_r,
                                               const unsigned* __restrict__ pref_t,
                                               const unsigned* __restrict__ gbase,
                                               unsigned* __restrict__ grec) {
    __shared__ unsigned recs[EPB];
    __shared__ unsigned short srow[SB + 1];
    int b = blockIdx.x, t = threadIdx.x;
    int base = b * EPB;
    int cnt = min(EPB, N_EDGES - base);
    for (int i = t; i < cnt; i += 256) recs[i] = rec_r[(size_t)base + i];
    for (int i = t; i < SB + 1; i += 256) srow[i] = srow_r[(size_t)b * (SB + 1) + i];
    __syncthreads();
    for (int s = t; s < SB; s += 256) {
        unsigned lo = srow[s], hi = srow[s + 1];
        if (lo == hi) continue;
        unsigned dst = gbase[s] + pref_t[(size_t)s * NBLK + b];
        for (unsigned i = lo; i < hi; ++i) grec[dst + (i - lo)] = recs[i];
    }
}

// within-bucket counting sort by local receiver (in-place) + CSR row_ptr
__global__ __launch_bounds__(256) void k_sort2(unsigned* __restrict__ grec,
                                               const unsigned* __restrict__ gbase,
                                               unsigned* __restrict__ row_ptr) {
    __shared__ unsigned recs[S2CAP];     // 48 KB
    __shared__ unsigned hist[256];
    __shared__ unsigned scan[256];
    __shared__ unsigned cur[256];
    int s = blockIdx.x, t = threadIdx.x;
    unsigned lo = gbase[s], hi = gbase[s + 1];
    unsigned cnt = min(hi - lo, (unsigned)S2CAP);
    for (unsigned i = t; i < cnt; i += 256) recs[i] = grec[lo + i];
    hist[t] = 0u;
    __syncthreads();
    for (unsigned i = t; i < cnt; i += 256) atomicAdd(&hist[recs[i] >> 17], 1u);
    __syncthreads();
    unsigned v = hist[t];
    scan[t] = v;
    __syncthreads();
    for (int off = 1; off < 256; off <<= 1) {
        unsigned x = (t >= off) ? scan[t - off] : 0u;
        __syncthreads();
        scan[t] += x;
        __syncthreads();
    }
    unsigned excl = scan[t] - v;
    {
        int n = (s << SBSH) + t;
        if (n <= N_NODES) row_ptr[n] = lo + excl;
    }
    cur[t] = excl;
    __syncthreads();
    for (unsigned i = t; i < cnt; i += 256) {
        unsigned rec = recs[i];
        unsigned pos = atomicAdd(&cur[rec >> 17], 1u);
        grec[lo + pos] = rec & 0x1FFFFu;
    }
}

// FUSED gather1 + gc2: block = 64 nodes x 5 lanes (320 thr).
// src is bf16 [N][20] (40B rows, fits XCD L2); lane q reads uint2 (4 bf16).
// Epilogue writes h2_pre as bf16.
__global__ __launch_bounds__(320) void k_gg1(const unsigned* __restrict__ row_ptr,
                                             const unsigned* __restrict__ grec,
                                             const unsigned* __restrict__ src,   // bf16 rows as uint2-pairs
                                             const float* __restrict__ W2,
                                             const float* __restrict__ b2,
                                             const float* __restrict__ rs_s,
                                             unsigned short* __restrict__ h2_pre) {
    __shared__ float h1[64 * 21];          // 5,376 B
    __shared__ float Wsh[GC_HID * GC_HID];
    __shared__ float bsh[GC_HID];
    int t = threadIdx.x;
    if (t < GC_HID * GC_HID) Wsh[t] = W2[t];
    if (t >= 400 && t < 400 + GC_HID) bsh[t - 400] = b2[t - 400];
    int nl = t / 5, q = t % 5;
    int node = blockIdx.x * 64 + nl;
    bool live = (node < N_NODES);
    unsigned lo = 0, hi = 0;
    if (live) { lo = row_ptr[node]; hi = row_ptr[node + 1]; }
    float4 a0 = make_float4(0.f, 0.f, 0.f, 0.f);
    float4 a1 = make_float4(0.f, 0.f, 0.f, 0.f);
    float4 a2 = make_float4(0.f, 0.f, 0.f, 0.f);
    float4 a3 = make_float4(0.f, 0.f, 0.f, 0.f);
    const uint2* sp = (const uint2*)src;
    unsigned e = lo;
    for (; e + 4 <= hi; e += 4) {
        unsigned s0 = grec[e], s1 = grec[e + 1], s2 = grec[e + 2], s3 = grec[e + 3];
        uint2 u0 = sp[s0 * 5 + q];
        uint2 u1 = sp[s1 * 5 + q];
        uint2 u2 = sp[s2 * 5 + q];
        uint2 u3 = sp[s3 * 5 + q];
        a0.x += bflo(u0.x); a0.y += bfhi(u0.x); a0.z += bflo(u0.y); a0.w += bfhi(u0.y);
        a1.x += bflo(u1.x); a1.y += bfhi(u1.x); a1.z += bflo(u1.y); a1.w += bfhi(u1.y);
        a2.x += bflo(u2.x); a2.y += bfhi(u2.x); a2.z += bflo(u2.y); a2.w += bfhi(u2.y);
        a3.x += bflo(u3.x); a3.y += bfhi(u3.x); a3.z += bflo(u3.y); a3.w += bfhi(u3.y);
    }
    for (; e < hi; ++e) {
        unsigned s0 = grec[e];
        uint2 u0 = sp[s0 * 5 + q];
        a0.x += bflo(u0.x); a0.y += bfhi(u0.x); a0.z += bflo(u0.y); a0.w += bfhi(u0.y);
    }
    a0.x += a1.x + a2.x + a3.x;
    a0.y += a1.y + a2.y + a3.y;
    a0.z += a1.z + a2.z + a3.z;
    a0.w += a1.w + a2.w + a3.w;
    if (live) {
        float sc = rsqrtf(fmaxf((float)(hi - lo), 1.0f));
        float* row = &h1[nl * 21 + q * 4];
        row[0] = a0.x * sc; row[1] = a0.y * sc;
        row[2] = a0.z * sc; row[3] = a0.w * sc;
    }
    __syncthreads();
    if (t < 64) {
        int nn = blockIdx.x * 64 + t;
        if (nn < N_NODES) {
            float hv[GC_HID];
#pragma unroll
            for (int i = 0; i < GC_HID; ++i) hv[i] = h1[t * 21 + i];
            float o[GC_HID];
#pragma unroll
            for (int j = 0; j < GC_HID; ++j) o[j] = bsh[j];
#pragma unroll
            for (int i = 0; i < GC_HID; ++i) {
                float x = hv[i];
#pragma unroll
                for (int j = 0; j < GC_HID; ++j) o[j] = fmaf(x, Wsh[i * GC_HID + j], o[j]);
            }
            float mx = -1e30f;
#pragma unroll
            for (int j = 0; j < GC_HID; ++j) { o[j] = fmaxf(o[j], 0.0f); mx = fmaxf(mx, o[j]); }
            float s = 0.0f;
#pragma unroll
            for (int j = 0; j < GC_HID; ++j) { o[j] = __expf(o[j] - mx); s += o[j]; }
            float inv = rs_s[nn] / s;
            unsigned pk[10];
#pragma unroll
            for (int i = 0; i < 10; ++i) {
                float v0 = o[2*i] * inv, v1 = o[2*i+1] * inv;
                pk[i] = (unsigned)f2bf(v0) | ((unsigned)f2bf(v1) << 16);
            }
            uint2* op = (uint2*)(h2_pre + (size_t)nn * GC_HID);
#pragma unroll
            for (int i = 0; i < 5; ++i)
                op[i] = make_uint2(pk[2*i], pk[2*i+1]);
        }
    }
}

// FUSED gather2 + encoder finish: 512 thr, 64 nodes. Waves 0-4 gather
// bf16 h2 into LDS [64][21] f32; barrier; all 8 waves run octet-split
// enc head (og = readfirstlane(wave), weights s_load).
__global__ __launch_bounds__(512) void k_gg2(const unsigned* __restrict__ row_ptr,
                                             const unsigned* __restrict__ grec,
                                             const unsigned* __restrict__ src,   // bf16 rows
                                             const unsigned short* __restrict__ pml,
                                             const float* __restrict__ Wmu,
                                             const float* __restrict__ bmu,
                                             const float* __restrict__ Wls,
                                             const float* __restrict__ bls,
                                             float* __restrict__ mu_out,
                                             float* __restrict__ ls_out) {
    __shared__ float h2s[64 * 21];         // 5,376 B
    int t = threadIdx.x;
    int n0 = blockIdx.x * 64;
    if (t < 320) {
        int nl = t / 5, q = t % 5;
        int node = n0 + nl;
        bool live = (node < N_NODES);
        unsigned lo = 0, hi = 0;
        if (live) { lo = row_ptr[node]; hi = row_ptr[node + 1]; }
        float4 a0 = make_float4(0.f, 0.f, 0.f, 0.f);
        float4 a1 = make_float4(0.f, 0.f, 0.f, 0.f);
        float4 a2 = make_float4(0.f, 0.f, 0.f, 0.f);
        float4 a3 = make_float4(0.f, 0.f, 0.f, 0.f);
        const uint2* sp = (const uint2*)src;
        unsigned e = lo;
        for (; e + 4 <= hi; e += 4) {
            unsigned s0 = grec[e], s1 = grec[e + 1], s2 = grec[e + 2], s3 = grec[e + 3];
            uint2 u0 = sp[s0 * 5 + q];
            uint2 u1 = sp[s1 * 5 + q];
            uint2 u2 = sp[s2 * 5 + q];
            uint2 u3 = sp[s3 * 5 + q];
            a0.x += bflo(u0.x); a0.y += bfhi(u0.x); a0.z += bflo(u0.y); a0.w += bfhi(u0.y);
            a1.x += bflo(u1.x); a1.y += bfhi(u1.x); a1.z += bflo(u1.y); a1.w += bfhi(u1.y);
            a2.x += bflo(u2.x); a2.y += bfhi(u2.x); a2.z += bflo(u2.y); a2.w += bfhi(u2.y);
            a3.x += bflo(u3.x); a3.y += bfhi(u3.x); a3.z += bflo(u3.y); a3.w += bfhi(u3.y);
        }
        for (; e < hi; ++e) {
            unsigned s0 = grec[e];
            uint2 u0 = sp[s0 * 5 + q];
            a0.x += bflo(u0.x); a0.y += bfhi(u0.x); a0.z += bflo(u0.y); a0.w += bfhi(u0.y);
        }
        a0.x += a1.x + a2.x + a3.x;
        a0.y += a1.y + a2.y + a3.y;
        a0.z += a1.z + a2.z + a3.z;
        a0.w += a1.w + a2.w + a3.w;
        if (live) {
            float sc = rsqrtf(fmaxf((float)(hi - lo), 1.0f));
            float* row = &h2s[nl * 21 + q * 4];
            row[0] = a0.x * sc; row[1] = a0.y * sc;
            row[2] = a0.z * sc; row[3] = a0.w * sc;
        }
    }
    __syncthreads();
    int wave = t >> 6, lane = t & 63;
    int og = __builtin_amdgcn_readfirstlane(wave);
    int half = og >> 2;
    int co = (og & 3) << 3;
    int node = n0 + lane;
    if (node >= N_NODES) return;
    const float* W  = half ? Wls : Wmu;
    const float* bb = half ? bls : bmu;
    float* out      = half ? ls_out : mu_out;

    uint4 p = *(const uint4*)(pml + (size_t)node * 64 + half * 32 + co);
    float acc[8];
    acc[0] = bf2f((unsigned short)(p.x & 0xFFFFu));
    acc[1] = bf2f((unsigned short)(p.x >> 16));
    acc[2] = bf2f((unsigned short)(p.y & 0xFFFFu));
    acc[3] = bf2f((unsigned short)(p.y >> 16));
    acc[4] = bf2f((unsigned short)(p.z & 0xFFFFu));
    acc[5] = bf2f((unsigned short)(p.z >> 16));
    acc[6] = bf2f((unsigned short)(p.w & 0xFFFFu));
    acc[7] = bf2f((unsigned short)(p.w >> 16));
#pragma unroll
    for (int j = 0; j < 8; ++j) acc[j] += bb[co + j];

#pragma unroll
    for (int i = 0; i < GC_HID; ++i) {
        float x = h2s[lane * 21 + i];
        const float* wr = W + i * Z_DIM + co;
#pragma unroll
        for (int j = 0; j < 8; ++j) acc[j] = fmaf(x, wr[j], acc[j]);
    }
    float4* op = (float4*)(out + (size_t)node * Z_DIM + co);
    op[0] = make_float4(acc[0], acc[1], acc[2], acc[3]);
    op[1] = make_float4(acc[4], acc[5], acc[6], acc[7]);
}

// FUSED gc1 + encoder-partials (R21 local optimum): 256 thr (4 waves =
// 4 output groups), 64 nodes/block, 1563 blocks. Packed weights
// (K$-resident 384B row per k, s_load broadcast), double-buffered x-tile.
// h_pre now written as bf16 [N][20].
__global__ __launch_bounds__(256) void k_gc1f(const float* __restrict__ nodes,
                                              const float* __restrict__ Wp,
                                              const float* __restrict__ b1,
                                              const float* __restrict__ rs_s,
                                              unsigned short* __restrict__ h_pre,
                                              unsigned short* __restrict__ pml) {
    __shared__ float tile[2][64 * 33];     // 16,896 B
    float* gb = &tile[0][0];               // aliased after last buf0 use
    int t = threadIdx.x;
    int g = __builtin_amdgcn_readfirstlane(t >> 6);  // 0..3: packed-col group
    int lane = t & 63;
    int n0 = blockIdx.x * 64;
    int node = n0 + lane;

    {
        int idx = t;
#pragma unroll
        for (int r = 0; r < 2; ++r, idx += 256) {
            int rr = idx >> 3, c4 = idx & 7;
            int gn = n0 + rr;
            float4 v = (gn < N_NODES)
                ? ((const float4*)nodes)[(size_t)gn * 64 + c4]
                : make_float4(0.f, 0.f, 0.f, 0.f);
            float* dst = &tile[0][rr * 33 + c4 * 4];
            dst[0] = v.x; dst[1] = v.y; dst[2] = v.z; dst[3] = v.w;
        }
    }
    __syncthreads();

    float acc[24];
#pragma unroll
    for (int j = 0; j < 24; ++j) acc[j] = 0.0f;

    for (int c = 0; c < 8; ++c) {
        float4 p0, p1;
        if (c < 7) {
            int idx = t, rr = idx >> 3, c4 = idx & 7, gn = n0 + rr;
            p0 = (gn < N_NODES)
                ? ((const float4*)nodes)[(size_t)gn * 64 + (c + 1) * 8 + c4]
                : make_float4(0.f, 0.f, 0.f, 0.f);
            idx = t + 256; rr = idx >> 3; c4 = idx & 7; gn = n0 + rr;
            p1 = (gn < N_NODES)
                ? ((const float4*)nodes)[(size_t)gn * 64 + (c + 1) * 8 + c4]
                : make_float4(0.f, 0.f, 0.f, 0.f);
        }
        const float* trow  = &tile[c & 1][lane * 33];
        const float* wbase = Wp + (size_t)(c * 32) * 96 + g * 24;
#pragma unroll 4
        for (int kk = 0; kk < 32; ++kk) {
            float x = trow[kk];
            const float* wr = wbase + kk * 96;
#pragma unroll
            for (int j = 0; j < 24; ++j) acc[j] = fmaf(x, wr[j], acc[j]);
        }
        if (c < 7) {
            int idx = t, rr = idx >> 3, c4 = idx & 7;
            float* dst = &tile[(c + 1) & 1][rr * 33 + c4 * 4];
            dst[0] = p0.x; dst[1] = p0.y; dst[2] = p0.z; dst[3] = p0.w;
            idx = t + 256; rr = idx >> 3; c4 = idx & 7;
            dst = &tile[(c + 1) & 1][rr * 33 + c4 * 4];
            dst[0] = p1.x; dst[1] = p1.y; dst[2] = p1.z; dst[3] = p1.w;
        }
        __syncthreads();
    }

    if (node < N_NODES) {
        if (g == 0) {
#pragma unroll
            for (int j = 0; j < GC_HID; ++j) gb[lane * 21 + j] = acc[j] + b1[j];
        } else {
            int base = (g - 1) * 24;
            unsigned short* pp = pml + (size_t)node * 64 + base;
            uint4 q0, q1, q2;
            q0.x = (unsigned)f2bf(acc[0]) | ((unsigned)f2bf(acc[1]) << 16);
            q0.y = (unsigned)f2bf(acc[2]) | ((unsigned)f2bf(acc[3]) << 16);
            q0.z = (unsigned)f2bf(acc[4]) | ((unsigned)f2bf(acc[5]) << 16);
            q0.w = (unsigned)f2bf(acc[6]) | ((unsigned)f2bf(acc[7]) << 16);
            q1.x = (unsigned)f2bf(acc[8]) | ((unsigned)f2bf(acc[9]) << 16);
            q1.y = (unsigned)f2bf(acc[10]) | ((unsigned)f2bf(acc[11]) << 16);
            q1.z = (unsigned)f2bf(acc[12]) | ((unsigned)f2bf(acc[13]) << 16);
            q1.w = (unsigned)f2bf(acc[14]) | ((unsigned)f2bf(acc[15]) << 16);
            q2.x = (unsigned)f2bf(acc[16]) | ((unsigned)f2bf(acc[17]) << 16);
            q2.y = (unsigned)f2bf(acc[18]) | ((unsigned)f2bf(acc[19]) << 16);
            q2.z = (unsigned)f2bf(acc[20]) | ((unsigned)f2bf(acc[21]) << 16);
            q2.w = (unsigned)f2bf(acc[22]) | ((unsigned)f2bf(acc[23]) << 16);
            ((uint4*)pp)[0] = q0;
            ((uint4*)pp)[1] = q1;
            if (g != 3) ((uint4*)pp)[2] = q2;
        }
    }
    __syncthreads();
    if (t < 64) {
        int nn = n0 + t;
        if (nn < N_NODES) {
            float v[GC_HID];
            float mx = -1e30f;
#pragma unroll
            for (int j = 0; j < GC_HID; ++j) {
                v[j] = fmaxf(gb[t * 21 + j], 0.0f);
                mx = fmaxf(mx, v[j]);
            }
            float s = 0.0f;
#pragma unroll
            for (int j = 0; j < GC_HID; ++j) {
                v[j] = __expf(v[j] - mx);
                s += v[j];
            }
            float inv = rs_s[nn] / s;
            unsigned pk[10];
#pragma unroll
            for (int i = 0; i < 10; ++i) {
                float v0 = v[2*i] * inv, v1 = v[2*i+1] * inv;
                pk[i] = (unsigned)f2bf(v0) | ((unsigned)f2bf(v1) << 16);
            }
            uint2* op = (uint2*)(h_pre + (size_t)nn * GC_HID);
#pragma unroll
            for (int i = 0; i < 5; ++i)
                op[i] = make_uint2(pk[2*i], pk[2*i+1]);
        }
    }
}

// FUSED decoder (decd + decx): 512 thr, 128 nodes/block, 782 blocks.
__global__ __launch_bounds__(512) void k_dec(const float* __restrict__ mu,
                                             const float* __restrict__ ls,
                                             const float* __restrict__ eps,
                                             const float* __restrict__ Wd1,
                                             const float* __restrict__ bd1,
                                             const float* __restrict__ Wd2,
                                             const float* __restrict__ bd2,
                                             float* __restrict__ X) {
    __shared__ float ds[128 * 41];         // 20,992 B
    int t = threadIdx.x;
    int wave = t >> 6, lane = t & 63;
    int n0 = blockIdx.x * 128;
    {
        int wu = __builtin_amdgcn_readfirstlane(wave);
        int qd = wu & 3;               // d-quarter: outputs qd*10 .. +9
        int nh = wu >> 2;              // node half
        int nrow = nh * 64 + lane;     // 0..127
        int node = n0 + nrow;
        if (node < N_NODES) {
            float z[Z_DIM];
            const float4* mp = (const float4*)(mu + (size_t)node * Z_DIM);
            const float4* lp = (const float4*)(ls + (size_t)node * Z_DIM);
            const float4* ep = (const float4*)(eps + (size_t)node * Z_DIM);
#pragma unroll
            for (int v = 0; v < Z_DIM / 4; ++v) {
                float4 m = mp[v], l = lp[v], e = ep[v];
                z[4*v+0] = m.x + (1e-4f + __expf(0.5f * l.x)) * e.x;
                z[4*v+1] = m.y + (1e-4f + __expf(0.5f * l.y)) * e.y;
                z[4*v+2] = m.z + (1e-4f + __expf(0.5f * l.z)) * e.z;
                z[4*v+3] = m.w + (1e-4f + __expf(0.5f * l.w)) * e.w;
            }
            float d[10];
#pragma unroll
            for (int j = 0; j < 10; ++j) d[j] = bd1[qd * 10 + j];
#pragma unroll
            for (int i = 0; i < Z_DIM; ++i) {
                float x = z[i];
                const float* wr = Wd1 + i * DEC_HID + qd * 10;
#pragma unroll
                for (int j = 0; j < 10; ++j) d[j] = fmaf(x, wr[j], d[j]);
            }
            float* dst = &ds[nrow * 41 + qd * 10];
#pragma unroll
            for (int j = 0; j < 10; ++j) dst[j] = fmaxf(d[j], 0.0f);
        }
    }
    __syncthreads();
#pragma unroll
    for (int p = 0; p < 2; ++p) {
        int ch = __builtin_amdgcn_readfirstlane(wave >> 1) + p * 4;  // 0..7
        int nrow = (wave & 1) * 64 + lane;     // 0..127
        int node = n0 + nrow;
        if (node < N_NODES) {
            int co = ch << 5;
            float o[32];
#pragma unroll
            for (int j = 0; j < 32; ++j) o[j] = bd2[co + j];
            const float* drow = &ds[nrow * 41];
#pragma unroll 8
            for (int k = 0; k < DEC_HID; ++k) {
                float x = drow[k];
                const float* wr = Wd2 + k * D_FEAT + co;
#pragma unroll
                for (int j = 0; j < 32; ++j) o[j] = fmaf(x, wr[j], o[j]);
            }
            float4* xp = (float4*)(X + (size_t)node * D_FEAT + co);
#pragma unroll
            for (int v = 0; v < 8; ++v)
                xp[v] = make_float4(o[4*v], o[4*v+1], o[4*v+2], o[4*v+3]);
        }
    }
}

extern "C" void kernel_launch(void* const* d_in, const int* in_sizes, int n_in,
                              void* d_out, int out_size, void* d_ws, size_t ws_size,
                              hipStream_t stream) {
    const float* nodes = (const float*)d_in[0];
    const int*   snd   = (const int*)d_in[1];
    const int*   rcv   = (const int*)d_in[2];
    const float* eps   = (const float*)d_in[3];
    const float* W1    = (const float*)d_in[4];
    const float* b1    = (const float*)d_in[5];
    const float* W2    = (const float*)d_in[6];
    const float* b2    = (const float*)d_in[7];
    const float* Wmu   = (const float*)d_in[8];
    const float* bmu   = (const float*)d_in[9];
    const float* Wls   = (const float*)d_in[10];
    const float* bls   = (const float*)d_in[11];
    const float* Wd1   = (const float*)d_in[12];
    const float* bd1   = (const float*)d_in[13];
    const float* Wd2   = (const float*)d_in[14];
    const float* bd2   = (const float*)d_in[15];

    char* ws = (char*)d_ws;
    unsigned short* h_pre    = (unsigned short*)(ws);              // bf16 [N][20]
    unsigned short* agg      = (unsigned short*)(ws + 8000000);    // bf16 [N][20]
    unsigned*       grec     = (unsigned*)(ws + 16000000);
    unsigned*       rec_r    = (unsigned*)(ws + 28804096);
    unsigned short* pml      = (unsigned short*)(ws + 28804096);   // overlays rec_r post-gscat
    unsigned short* srow_r   = (unsigned short*)(ws + 41608192);
    unsigned*       pref_t   = (unsigned*)(ws + 42836720);
    unsigned*       row_ptr  = (unsigned*)(ws + 45287504);
    unsigned*       gtot     = (unsigned*)(ws + 45687508);
    unsigned*       gbase    = (unsigned*)(ws + 45689076);
    float*          rs_s     = (float*)(ws + 45690648);
    unsigned char*  rec_s    = (unsigned char*)(ws + 46090648);
    unsigned short* srow_s   = (unsigned short*)(ws + 49291672);
    float*          Wpack    = (float*)(ws + 50520192);

    float* X      = (float*)d_out;
    float* mu_out = X + (size_t)N_NODES * D_FEAT;
    float* ls_out = mu_out + (size_t)N_NODES * Z_DIM;

    k_wpack<<<256, 96, 0, stream>>>(W1, Wmu, Wls, Wpack);
    k_sort<<<NBLK, 512, 0, stream>>>(snd, rcv, rec_r, rec_s, srow_r, srow_s);
    k_degs<<<SB, 512, 0, stream>>>(rec_s, srow_s, rs_s);
    k_scanB<<<SB, 256, 0, stream>>>(srow_r, pref_t, gtot);
    k_scanG<<<1, 512, 0, stream>>>(gtot, gbase);
    k_gscat<<<NBLK, 256, 0, stream>>>(rec_r, srow_r, pref_t, gbase, grec);
    k_sort2<<<SB, 256, 0, stream>>>(grec, gbase, row_ptr);

    k_gc1f<<<1563, 256, 0, stream>>>(nodes, Wpack, b1, rs_s, h_pre, pml);
    // fused gather1 + gc2 -> h2_pre (bf16) in agg
    k_gg1<<<1563, 320, 0, stream>>>(row_ptr, grec, (const unsigned*)h_pre,
                                    W2, b2, rs_s, agg);
    // fused gather2 + encoder head -> mu/ls
    k_gg2<<<1563, 512, 0, stream>>>(row_ptr, grec, (const unsigned*)agg, pml,
                                    Wmu, bmu, Wls, bls, mu_out, ls_out);
    // fused decoder (z + d + X)
    k_dec<<<782, 512, 0, stream>>>(mu_out, ls_out, eps, Wd1, bd1, Wd2, bd2, X);
}